// Round 3
// baseline (229.584 us; speedup 1.0000x reference)
//
#include <hip/hip_runtime.h>
#include <stdint.h>

typedef __attribute__((ext_vector_type(8))) __bf16  bf16x8;
typedef __attribute__((ext_vector_type(4))) float   f32x4;
typedef __attribute__((ext_vector_type(8))) ushort  u16x8;
typedef __attribute__((ext_vector_type(4))) ushort  u16x4;

#define LOG2E 1.44269504088896f

__device__ __forceinline__ ushort f2bf(float f) {
  uint32_t u = __float_as_uint(f);
  u += 0x7fffu + ((u >> 16) & 1u);   // RNE
  return (ushort)(u >> 16);
}
__device__ __forceinline__ float bf2f(ushort h) {
  return __uint_as_float(((uint32_t)h) << 16);
}
__device__ __forceinline__ void gload16(const void* g, void* l) {
  __builtin_amdgcn_global_load_lds((const __attribute__((address_space(1))) void*)g,
                                   (__attribute__((address_space(3))) void*)l, 16, 0, 0);
}
__device__ __forceinline__ f32x4 mfma16(bf16x8 a, bf16x8 b, f32x4 c) {
  return __builtin_amdgcn_mfma_f32_16x16x32_bf16(a, b, c, 0, 0, 0);
}
// LDS XOR swizzle for 128B rows (m214 G4 fix): byte ^= (row&7)<<4
__device__ __forceinline__ int swz(int row, int byteoff) {
  return row * 128 + (byteoff ^ ((row & 7) << 4));
}

// ---------------- fp32 -> bf16 (weights) ----------------
__global__ __launch_bounds__(256) void cvt_f32_bf16(const float* __restrict__ src,
                                                    ushort* __restrict__ dst, int n8) {
  int i = blockIdx.x * 256 + threadIdx.x;
  if (i >= n8) return;
  const f32x4* s = (const f32x4*)src;
  f32x4 a = s[2 * i], b = s[2 * i + 1];
  u16x8 o;
  o[0] = f2bf(a[0]); o[1] = f2bf(a[1]); o[2] = f2bf(a[2]); o[3] = f2bf(a[3]);
  o[4] = f2bf(b[0]); o[5] = f2bf(b[1]); o[6] = f2bf(b[2]); o[7] = f2bf(b[3]);
  ((u16x8*)dst)[i] = o;
}

// ---------------- QKV projection GEMM ----------------
// out = X[4096,1024](f32) @ W^T(bf16) + bias ; 128x128 tile, BK=32, 4 waves 2x2.
// z==0/1 -> Q/K layout [B,H,S,Dh]; z==2 -> V transposed [B,H,Dh,S].
struct QKVArgs {
  const float* A0; const float* A1; const float* A2;
  const ushort* W0; const ushort* W1; const ushort* W2;
  const float* b0; const float* b1; const float* b2;
  ushort* Qo; ushort* Ko; ushort* Vo;
};

__global__ __launch_bounds__(256) void qkv_gemm(QKVArgs args) {
  __shared__ ushort Ash[128 * 32];
  __shared__ ushort Bsh[128 * 32];

  const int z = blockIdx.z;
  const float*  A32  = z == 0 ? args.A0 : (z == 1 ? args.A1 : args.A2);
  const ushort* Wb   = z == 0 ? args.W0 : (z == 1 ? args.W1 : args.W2);
  const float*  bias = z == 0 ? args.b0 : (z == 1 ? args.b1 : args.b2);

  const int tid = threadIdx.x;
  const int lane = tid & 63, wid = tid >> 6;
  const int l15 = lane & 15, g = lane >> 4;
  const int wr = wid >> 1, wc = wid & 1;
  const int tm = blockIdx.x * 128, tn = blockIdx.y * 128;

  const f32x4 fz = {0.f, 0.f, 0.f, 0.f};
  f32x4 acc[4][4];
#pragma unroll
  for (int m = 0; m < 4; ++m)
#pragma unroll
    for (int n = 0; n < 4; ++n) acc[m][n] = fz;

  const int arow = tid >> 1, ahalf = tid & 1;

  for (int kt = 0; kt < 1024; kt += 32) {
    // B tile (bf16 weights) via global_load_lds, 2 chunks of 1KB per wave
#pragma unroll
    for (int c = 0; c < 2; ++c) {
      const int chunk = wid * 2 + c;
      const int off = chunk * 1024 + lane * 16;
      const int row = off >> 6;
      const int ke = (off & 63) >> 1;
      gload16(Wb + (size_t)(tn + row) * 1024 + kt + ke, &Bsh[chunk * 512]);
    }
    // A tile: fp32 load + cvt + ds_write (16 elems per thread)
    {
      const float* gp = A32 + (size_t)(tm + arow) * 1024 + kt + ahalf * 16;
      f32x4 v0 = ((const f32x4*)gp)[0];
      f32x4 v1 = ((const f32x4*)gp)[1];
      f32x4 v2 = ((const f32x4*)gp)[2];
      f32x4 v3 = ((const f32x4*)gp)[3];
      u16x8 w0, w1;
      w0[0] = f2bf(v0[0]); w0[1] = f2bf(v0[1]); w0[2] = f2bf(v0[2]); w0[3] = f2bf(v0[3]);
      w0[4] = f2bf(v1[0]); w0[5] = f2bf(v1[1]); w0[6] = f2bf(v1[2]); w0[7] = f2bf(v1[3]);
      w1[0] = f2bf(v2[0]); w1[1] = f2bf(v2[1]); w1[2] = f2bf(v2[2]); w1[3] = f2bf(v2[3]);
      w1[4] = f2bf(v3[0]); w1[5] = f2bf(v3[1]); w1[6] = f2bf(v3[2]); w1[7] = f2bf(v3[3]);
      *(u16x8*)&Ash[arow * 32 + ahalf * 16] = w0;
      *(u16x8*)&Ash[arow * 32 + ahalf * 16 + 8] = w1;
    }
    __syncthreads();

    bf16x8 af[4], bfr[4];
#pragma unroll
    for (int m = 0; m < 4; ++m)
      af[m] = *(const bf16x8*)&Ash[(wr * 64 + m * 16 + l15) * 32 + g * 8];
#pragma unroll
    for (int n = 0; n < 4; ++n)
      bfr[n] = *(const bf16x8*)&Bsh[(wc * 64 + n * 16 + l15) * 32 + g * 8];
#pragma unroll
    for (int m = 0; m < 4; ++m)
#pragma unroll
      for (int n = 0; n < 4; ++n) acc[m][n] = mfma16(af[m], bfr[n], acc[m][n]);
    __syncthreads();
  }

  // epilogue
#pragma unroll
  for (int n = 0; n < 4; ++n) {
    const int col = tn + wc * 64 + n * 16 + l15;
    const float bv = bias[col];
    const int h = col >> 6, d = col & 63;
#pragma unroll
    for (int m = 0; m < 4; ++m) {
      const int row0 = tm + wr * 64 + m * 16 + g * 4;
      if (z == 2) {            // V^T : [B,H,Dh,S]
        const int b = row0 >> 11, s0 = row0 & 2047;
        u16x4 pk;
#pragma unroll
        for (int r = 0; r < 4; ++r) pk[r] = f2bf(acc[m][n][r] + bv);
        *(u16x4*)&args.Vo[((size_t)((b * 16 + h) * 64 + d)) * 2048 + s0] = pk;
      } else {                 // Q/K : [B,H,S,Dh]
        ushort* O = z ? args.Ko : args.Qo;
#pragma unroll
        for (int r = 0; r < 4; ++r) {
          const int row = row0 + r;
          const int b = row >> 11, s = row & 2047;
          O[((size_t)(b * 16 + h) * 2048 + s) * 64 + d] = f2bf(acc[m][n][r] + bv);
        }
      }
    }
  }
}

// ---------------- flash attention ----------------
// grid (S/64, B*H); 4 waves x 16 q-rows; KV tile 64. K,V^T in swizzled LDS.
__global__ __launch_bounds__(256) void attn_fwd(const ushort* __restrict__ Qb,
                                                const ushort* __restrict__ Kb,
                                                const ushort* __restrict__ VTb,
                                                ushort* __restrict__ ctxb) {
  __shared__ char Ksh[64 * 128];
  __shared__ char Vsh[64 * 128];
  __shared__ char Psh[4 * 16 * 128];

  const int tid = threadIdx.x;
  const int lane = tid & 63, wid = tid >> 6;
  const int l15 = lane & 15, g = lane >> 4;
  const int bh = blockIdx.y;
  const int qb = blockIdx.x * 64;

  const ushort* Qh = Qb + (size_t)bh * 2048 * 64;
  const ushort* Kh = Kb + (size_t)bh * 2048 * 64;
  const ushort* Vh = VTb + (size_t)bh * 64 * 2048;

  // Q fragments, pre-scaled by 1/sqrt(Dh)=0.125 (exact in bf16)
  bf16x8 aq[2];
  {
    const int qr = qb + wid * 16 + l15;
#pragma unroll
    for (int kk = 0; kk < 2; ++kk) {
      u16x8 raw = *(const u16x8*)&Qh[(size_t)qr * 64 + kk * 32 + g * 8];
      u16x8 sc;
#pragma unroll
      for (int j = 0; j < 8; ++j) sc[j] = f2bf(bf2f(raw[j]) * 0.125f);
      aq[kk] = __builtin_bit_cast(bf16x8, sc);
    }
  }

  const f32x4 fz = {0.f, 0.f, 0.f, 0.f};
  float mrow[4], lrow[4];
  f32x4 o[4];
#pragma unroll
  for (int r = 0; r < 4; ++r) { mrow[r] = -1e30f; lrow[r] = 0.f; }
#pragma unroll
  for (int n = 0; n < 4; ++n) o[n] = fz;

  const int srow = tid >> 2, sq = tid & 3;

  for (int kt = 0; kt < 2048; kt += 64) {
    {  // stage K tile [64 x 64] and V^T tile [64 x 64] (swizzled)
      const ushort* kp = &Kh[(size_t)(kt + srow) * 64 + sq * 16];
      u16x8 k0 = *(const u16x8*)kp;
      u16x8 k1 = *(const u16x8*)(kp + 8);
      *(u16x8*)(Ksh + swz(srow, sq * 32)) = k0;
      *(u16x8*)(Ksh + swz(srow, sq * 32 + 16)) = k1;
      const ushort* vp = &Vh[(size_t)srow * 2048 + kt + sq * 16];
      u16x8 v0 = *(const u16x8*)vp;
      u16x8 v1 = *(const u16x8*)(vp + 8);
      *(u16x8*)(Vsh + swz(srow, sq * 32)) = v0;
      *(u16x8*)(Vsh + swz(srow, sq * 32 + 16)) = v1;
    }
    __syncthreads();

    // scores: 4 col-tiles of 16 k-rows
    f32x4 sc4[4];
#pragma unroll
    for (int n = 0; n < 4; ++n) {
      bf16x8 b0 = *(const bf16x8*)(Ksh + swz(n * 16 + l15, g * 16));
      bf16x8 b1 = *(const bf16x8*)(Ksh + swz(n * 16 + l15, 64 + g * 16));
      f32x4 zv = fz;
      zv = mfma16(aq[0], b0, zv);
      zv = mfma16(aq[1], b1, zv);
      sc4[n] = zv;
    }

    // online softmax (rows r = 4g+r, 16-lane butterfly reduce)
    float scale[4];
#pragma unroll
    for (int r = 0; r < 4; ++r) {
      float v = fmaxf(fmaxf(sc4[0][r], sc4[1][r]), fmaxf(sc4[2][r], sc4[3][r]));
      v = fmaxf(v, __shfl_xor(v, 1));
      v = fmaxf(v, __shfl_xor(v, 2));
      v = fmaxf(v, __shfl_xor(v, 4));
      v = fmaxf(v, __shfl_xor(v, 8));
      const float mn = fmaxf(mrow[r], v);
      scale[r] = __builtin_amdgcn_exp2f((mrow[r] - mn) * LOG2E);
      mrow[r] = mn;
    }
#pragma unroll
    for (int n = 0; n < 4; ++n) {
#pragma unroll
      for (int r = 0; r < 4; ++r) {
        const float p = __builtin_amdgcn_exp2f((sc4[n][r] - mrow[r]) * LOG2E);
        sc4[n][r] = p;
        const int prow = g * 4 + r;
        *(ushort*)(Psh + wid * 2048 + prow * 128 +
                   (((n * 16 + l15) * 2) ^ ((prow & 7) << 4))) = f2bf(p);
      }
    }
#pragma unroll
    for (int r = 0; r < 4; ++r) {
      float rs = sc4[0][r] + sc4[1][r] + sc4[2][r] + sc4[3][r];
      rs += __shfl_xor(rs, 1);
      rs += __shfl_xor(rs, 2);
      rs += __shfl_xor(rs, 4);
      rs += __shfl_xor(rs, 8);
      lrow[r] = lrow[r] * scale[r] + rs;
#pragma unroll
      for (int n = 0; n < 4; ++n) o[n][r] *= scale[r];
    }

    // PV: o[16 x 64] += P[16 x 64] @ V[64 x 64]
#pragma unroll
    for (int kk = 0; kk < 2; ++kk) {
      bf16x8 ap = *(const bf16x8*)(Psh + wid * 2048 + swz(l15, kk * 64 + g * 16));
#pragma unroll
      for (int n = 0; n < 4; ++n) {
        bf16x8 bv = *(const bf16x8*)(Vsh + swz(n * 16 + l15, kk * 64 + g * 16));
        o[n] = mfma16(ap, bv, o[n]);
      }
    }
    __syncthreads();
  }

  // epilogue: ctx[B,S,EMB] bf16
  const int b = bh >> 4, h = bh & 15;
#pragma unroll
  for (int r = 0; r < 4; ++r) {
    const float inv = 1.0f / lrow[r];
    const int s = qb + wid * 16 + g * 4 + r;
    const size_t base = ((size_t)(b * 2048 + s)) * 1024 + h * 64;
#pragma unroll
    for (int n = 0; n < 4; ++n)
      ctxb[base + n * 16 + l15] = f2bf(o[n][r] * inv);
  }
}

// ---------------- output projection: ctx(bf16) @ Wo^T + bo -> fp32 ----------------
__global__ __launch_bounds__(256) void out_gemm(const ushort* __restrict__ A16,
                                                const ushort* __restrict__ Wb,
                                                const float* __restrict__ bias,
                                                float* __restrict__ O) {
  __shared__ ushort Ash[128 * 32];
  __shared__ ushort Bsh[128 * 32];

  const int tid = threadIdx.x;
  const int lane = tid & 63, wid = tid >> 6;
  const int l15 = lane & 15, g = lane >> 4;
  const int wr = wid >> 1, wc = wid & 1;
  const int tm = blockIdx.x * 128, tn = blockIdx.y * 128;

  const f32x4 fz = {0.f, 0.f, 0.f, 0.f};
  f32x4 acc[4][4];
#pragma unroll
  for (int m = 0; m < 4; ++m)
#pragma unroll
    for (int n = 0; n < 4; ++n) acc[m][n] = fz;

  for (int kt = 0; kt < 1024; kt += 32) {
#pragma unroll
    for (int c = 0; c < 2; ++c) {
      const int chunk = wid * 2 + c;
      const int off = chunk * 1024 + lane * 16;
      const int row = off >> 6;
      const int ke = (off & 63) >> 1;
      gload16(Wb + (size_t)(tn + row) * 1024 + kt + ke, &Bsh[chunk * 512]);
      gload16(A16 + (size_t)(tm + row) * 1024 + kt + ke, &Ash[chunk * 512]);
    }
    __syncthreads();

    bf16x8 af[4], bfr[4];
#pragma unroll
    for (int m = 0; m < 4; ++m)
      af[m] = *(const bf16x8*)&Ash[(wr * 64 + m * 16 + l15) * 32 + g * 8];
#pragma unroll
    for (int n = 0; n < 4; ++n)
      bfr[n] = *(const bf16x8*)&Bsh[(wc * 64 + n * 16 + l15) * 32 + g * 8];
#pragma unroll
    for (int m = 0; m < 4; ++m)
#pragma unroll
      for (int n = 0; n < 4; ++n) acc[m][n] = mfma16(af[m], bfr[n], acc[m][n]);
    __syncthreads();
  }

#pragma unroll
  for (int n = 0; n < 4; ++n) {
    const int col = tn + wc * 64 + n * 16 + l15;
    const float bv = bias[col];
#pragma unroll
    for (int m = 0; m < 4; ++m) {
      const int row0 = tm + wr * 64 + m * 16 + g * 4;
#pragma unroll
      for (int r = 0; r < 4; ++r)
        O[(size_t)(row0 + r) * 1024 + col] = acc[m][n][r] + bv;
    }
  }
}

extern "C" void kernel_launch(void* const* d_in, const int* in_sizes, int n_in,
                              void* d_out, int out_size, void* d_ws, size_t ws_size,
                              hipStream_t stream) {
  const float* query = (const float*)d_in[0];
  const float* key_  = (const float*)d_in[1];
  const float* value = (const float*)d_in[2];
  const float* Wq = (const float*)d_in[3];
  const float* bq = (const float*)d_in[4];
  const float* Wk = (const float*)d_in[5];
  const float* bk = (const float*)d_in[6];
  const float* Wv = (const float*)d_in[7];
  const float* bv = (const float*)d_in[8];
  const float* Wo = (const float*)d_in[9];
  const float* bo = (const float*)d_in[10];

  ushort* ws = (ushort*)d_ws;
  ushort* Wqb = ws;                       // 1M elems each
  ushort* Wkb = ws + (1u << 20);
  ushort* Wvb = ws + (2u << 20);
  ushort* Wob = ws + (3u << 20);
  ushort* Qb  = ws + (4u << 20);          // 4M elems each
  ushort* Kb  = Qb + (4u << 20);
  ushort* VTb = Kb + (4u << 20);
  ushort* ctx = VTb + (4u << 20);         // total 20M elems = 40 MiB

  dim3 blk(256);
  cvt_f32_bf16<<<512, blk, 0, stream>>>(Wq, Wqb, 131072);
  cvt_f32_bf16<<<512, blk, 0, stream>>>(Wk, Wkb, 131072);
  cvt_f32_bf16<<<512, blk, 0, stream>>>(Wv, Wvb, 131072);
  cvt_f32_bf16<<<512, blk, 0, stream>>>(Wo, Wob, 131072);

  QKVArgs a;
  a.A0 = query; a.A1 = key_; a.A2 = value;
  a.W0 = Wqb;  a.W1 = Wkb;  a.W2 = Wvb;
  a.b0 = bq;   a.b1 = bk;   a.b2 = bv;
  a.Qo = Qb;   a.Ko = Kb;   a.Vo = VTb;
  qkv_gemm<<<dim3(32, 8, 3), blk, 0, stream>>>(a);

  attn_fwd<<<dim3(32, 32), blk, 0, stream>>>(Qb, Kb, VTb, ctx);

  out_gemm<<<dim3(32, 8), blk, 0, stream>>>(ctx, Wob, bo, (float*)d_out);
}

// Round 4
// 171.014 us; speedup vs baseline: 1.3425x; 1.3425x over previous
//
#include <hip/hip_runtime.h>
#include <stdint.h>

typedef __attribute__((ext_vector_type(8)))  __bf16 bf16x8;
typedef __attribute__((ext_vector_type(4)))  float  f32x4;
typedef __attribute__((ext_vector_type(16))) float  f32x16;
typedef __attribute__((ext_vector_type(8)))  ushort u16x8;
typedef __attribute__((ext_vector_type(4)))  ushort u16x4;
typedef __attribute__((ext_vector_type(4)))  uint   u32x4;

#define LOG2E 1.44269504088896f

__device__ __forceinline__ ushort f2bf(float f) {
  uint32_t u = __float_as_uint(f);
  u += 0x7fffu + ((u >> 16) & 1u);   // RNE
  return (ushort)(u >> 16);
}
__device__ __forceinline__ float bf2f(ushort h) {
  return __uint_as_float(((uint32_t)h) << 16);
}
__device__ __forceinline__ void gload16(const void* g, void* l) {
  __builtin_amdgcn_global_load_lds((const __attribute__((address_space(1))) void*)g,
                                   (__attribute__((address_space(3))) void*)l, 16, 0, 0);
}
__device__ __forceinline__ f32x4 mfma16(bf16x8 a, bf16x8 b, f32x4 c) {
  return __builtin_amdgcn_mfma_f32_16x16x32_bf16(a, b, c, 0, 0, 0);
}
__device__ __forceinline__ f32x16 mfma32(bf16x8 a, bf16x8 b, f32x16 c) {
  return __builtin_amdgcn_mfma_f32_32x32x16_bf16(a, b, c, 0, 0, 0);
}
// LDS XOR swizzle for 128B rows (m214 G4): byte ^= (row&7)<<4
__device__ __forceinline__ int swz(int row, int byteoff) {
  return row * 128 + (byteoff ^ ((row & 7) << 4));
}
__device__ __forceinline__ uint cvtpk(float lo, float hi) {
  uint w;
  asm("v_cvt_pk_bf16_f32 %0, %1, %2" : "=v"(w) : "v"(lo), "v"(hi));
  return w;
}
__device__ __forceinline__ void plswap(uint& a, uint& b) {
  asm("v_permlane32_swap_b32 %0, %1" : "+v"(a), "+v"(b));
}

// ---------------- fp32 -> bf16 (weights) ----------------
__global__ __launch_bounds__(256) void cvt_f32_bf16(const float* __restrict__ src,
                                                    ushort* __restrict__ dst, int n8) {
  int i = blockIdx.x * 256 + threadIdx.x;
  if (i >= n8) return;
  const f32x4* s = (const f32x4*)src;
  f32x4 a = s[2 * i], b = s[2 * i + 1];
  u16x8 o;
  o[0] = f2bf(a[0]); o[1] = f2bf(a[1]); o[2] = f2bf(a[2]); o[3] = f2bf(a[3]);
  o[4] = f2bf(b[0]); o[5] = f2bf(b[1]); o[6] = f2bf(b[2]); o[7] = f2bf(b[3]);
  ((u16x8*)dst)[i] = o;
}

// ---------------- QKV projection GEMM (unchanged, known-good) ----------------
struct QKVArgs {
  const float* A0; const float* A1; const float* A2;
  const ushort* W0; const ushort* W1; const ushort* W2;
  const float* b0; const float* b1; const float* b2;
  ushort* Qo; ushort* Ko; ushort* Vo;
};

__global__ __launch_bounds__(256) void qkv_gemm(QKVArgs args) {
  __shared__ ushort Ash[128 * 32];
  __shared__ ushort Bsh[128 * 32];

  const int z = blockIdx.z;
  const float*  A32  = z == 0 ? args.A0 : (z == 1 ? args.A1 : args.A2);
  const ushort* Wb   = z == 0 ? args.W0 : (z == 1 ? args.W1 : args.W2);
  const float*  bias = z == 0 ? args.b0 : (z == 1 ? args.b1 : args.b2);

  const int tid = threadIdx.x;
  const int lane = tid & 63, wid = tid >> 6;
  const int l15 = lane & 15, g = lane >> 4;
  const int wr = wid >> 1, wc = wid & 1;
  const int tm = blockIdx.x * 128, tn = blockIdx.y * 128;

  const f32x4 fz = {0.f, 0.f, 0.f, 0.f};
  f32x4 acc[4][4];
#pragma unroll
  for (int m = 0; m < 4; ++m)
#pragma unroll
    for (int n = 0; n < 4; ++n) acc[m][n] = fz;

  const int arow = tid >> 1, ahalf = tid & 1;

  for (int kt = 0; kt < 1024; kt += 32) {
#pragma unroll
    for (int c = 0; c < 2; ++c) {
      const int chunk = wid * 2 + c;
      const int off = chunk * 1024 + lane * 16;
      const int row = off >> 6;
      const int ke = (off & 63) >> 1;
      gload16(Wb + (size_t)(tn + row) * 1024 + kt + ke, &Bsh[chunk * 512]);
    }
    {
      const float* gp = A32 + (size_t)(tm + arow) * 1024 + kt + ahalf * 16;
      f32x4 v0 = ((const f32x4*)gp)[0];
      f32x4 v1 = ((const f32x4*)gp)[1];
      f32x4 v2 = ((const f32x4*)gp)[2];
      f32x4 v3 = ((const f32x4*)gp)[3];
      u16x8 w0, w1;
      w0[0] = f2bf(v0[0]); w0[1] = f2bf(v0[1]); w0[2] = f2bf(v0[2]); w0[3] = f2bf(v0[3]);
      w0[4] = f2bf(v1[0]); w0[5] = f2bf(v1[1]); w0[6] = f2bf(v1[2]); w0[7] = f2bf(v1[3]);
      w1[0] = f2bf(v2[0]); w1[1] = f2bf(v2[1]); w1[2] = f2bf(v2[2]); w1[3] = f2bf(v2[3]);
      w1[4] = f2bf(v3[0]); w1[5] = f2bf(v3[1]); w1[6] = f2bf(v3[2]); w1[7] = f2bf(v3[3]);
      *(u16x8*)&Ash[arow * 32 + ahalf * 16] = w0;
      *(u16x8*)&Ash[arow * 32 + ahalf * 16 + 8] = w1;
    }
    __syncthreads();

    bf16x8 af[4], bfr[4];
#pragma unroll
    for (int m = 0; m < 4; ++m)
      af[m] = *(const bf16x8*)&Ash[(wr * 64 + m * 16 + l15) * 32 + g * 8];
#pragma unroll
    for (int n = 0; n < 4; ++n)
      bfr[n] = *(const bf16x8*)&Bsh[(wc * 64 + n * 16 + l15) * 32 + g * 8];
#pragma unroll
    for (int m = 0; m < 4; ++m)
#pragma unroll
      for (int n = 0; n < 4; ++n) acc[m][n] = mfma16(af[m], bfr[n], acc[m][n]);
    __syncthreads();
  }

#pragma unroll
  for (int n = 0; n < 4; ++n) {
    const int col = tn + wc * 64 + n * 16 + l15;
    const float bv = bias[col];
    const int h = col >> 6, d = col & 63;
#pragma unroll
    for (int m = 0; m < 4; ++m) {
      const int row0 = tm + wr * 64 + m * 16 + g * 4;
      if (z == 2) {            // V^T : [B,H,Dh,S]
        const int b = row0 >> 11, s0 = row0 & 2047;
        u16x4 pk;
#pragma unroll
        for (int r = 0; r < 4; ++r) pk[r] = f2bf(acc[m][n][r] + bv);
        *(u16x4*)&args.Vo[((size_t)((b * 16 + h) * 64 + d)) * 2048 + s0] = pk;
      } else {                 // Q/K : [B,H,S,Dh]
        ushort* O = z ? args.Ko : args.Qo;
#pragma unroll
        for (int r = 0; r < 4; ++r) {
          const int row = row0 + r;
          const int b = row >> 11, s = row & 2047;
          O[((size_t)(b * 16 + h) * 2048 + s) * 64 + d] = f2bf(acc[m][n][r] + bv);
        }
      }
    }
  }
}

// ---------------- flash attention, 32x32 swapped-QK^T, in-register softmax ----
// grid (S/128, B*H); 4 waves x 32 q-rows; KV tile 64.
// P^T = mfma32(K_frag, Q_frag): col=q=lane&31, row k=(reg&3)+8*(reg>>2)+4*hi.
// Softmax state (m,l) is per-lane (lane owns q=lane&31). P->A-frag via
// cvt_pk_bf16 + permlane32_swap (T12). Defer-max THR=8 (T13). Split staging (T14).
__global__ __launch_bounds__(256) void attn_fwd(const ushort* __restrict__ Qb,
                                                const ushort* __restrict__ Kb,
                                                const ushort* __restrict__ VTb,
                                                ushort* __restrict__ ctxb) {
  __shared__ char Ksh[64 * 128];     // K tile [kv=64][d=64] bf16, swizzled
  __shared__ char Vsh[64 * 128];     // V^T tile [d=64][kv=64] bf16, swizzled
  __shared__ float Ssc[4][32];       // per-wave q-indexed broadcast slab

  const int tid = threadIdx.x;
  const int lane = tid & 63, wid = tid >> 6;
  const int l31 = lane & 31, hi = lane >> 5;
  const int bh = blockIdx.y;
  const int q0 = blockIdx.x * 128 + wid * 32;

  const ushort* Qh = Qb + (size_t)bh * 2048 * 64;
  const ushort* Kh = Kb + (size_t)bh * 2048 * 64;
  const ushort* Vh = VTb + (size_t)bh * 64 * 2048;

  // Q fragments: lane holds Q[q0+l31][dt*16 + hi*8 + j], pre-scaled by 0.125
  bf16x8 qf[4];
  {
    const ushort* qrow = Qh + (size_t)(q0 + l31) * 64;
#pragma unroll
    for (int dt = 0; dt < 4; ++dt) {
      u16x8 raw = *(const u16x8*)&qrow[dt * 16 + hi * 8];
      u16x8 sc;
#pragma unroll
      for (int j = 0; j < 8; ++j) sc[j] = f2bf(bf2f(raw[j]) * 0.125f);
      qf[dt] = __builtin_bit_cast(bf16x8, sc);
    }
  }

  f32x16 o0 = {}, o1 = {};
  float m = -1e30f, lsum = 0.f;

  const int si = tid >> 2, sc4i = tid & 3;   // staging: row, chunk
  const ushort* kg = &Kh[(size_t)si * 64 + sc4i * 16];
  const ushort* vg = &Vh[(size_t)si * 2048 + sc4i * 16];

  u16x8 kr0, kr1, vr0, vr1;
  // prologue: stage tile 0
  kr0 = *(const u16x8*)kg;  kr1 = *(const u16x8*)(kg + 8);
  vr0 = *(const u16x8*)vg;  vr1 = *(const u16x8*)(vg + 8);
  *(u16x8*)(Ksh + swz(si, sc4i * 32))      = kr0;
  *(u16x8*)(Ksh + swz(si, sc4i * 32 + 16)) = kr1;
  *(u16x8*)(Vsh + swz(si, sc4i * 32))      = vr0;
  *(u16x8*)(Vsh + swz(si, sc4i * 32 + 16)) = vr1;
  __syncthreads();

  for (int t = 0; t < 32; ++t) {
    // T14: issue next tile's global loads before compute
    if (t + 1 < 32) {
      const int kt2 = (t + 1) * 64;
      kr0 = *(const u16x8*)(kg + (size_t)kt2 * 64);
      kr1 = *(const u16x8*)(kg + (size_t)kt2 * 64 + 8);
      vr0 = *(const u16x8*)(vg + kt2);
      vr1 = *(const u16x8*)(vg + kt2 + 8);
    }

    // QK^T: P^T[s] = sum_dt mfma32(Kfrag(s,dt), qf[dt])
    f32x16 P0 = {}, P1 = {};
    __builtin_amdgcn_s_setprio(1);
#pragma unroll
    for (int dt = 0; dt < 4; ++dt) {
      bf16x8 kf0 = *(const bf16x8*)(Ksh + swz(l31,      dt * 32 + hi * 16));
      bf16x8 kf1 = *(const bf16x8*)(Ksh + swz(32 + l31, dt * 32 + hi * 16));
      P0 = mfma32(kf0, qf[dt], P0);
      P1 = mfma32(kf1, qf[dt], P1);
    }
    __builtin_amdgcn_s_setprio(0);

    // ---- online softmax (per-lane state for q = l31) ----
    float pm = P0[0];
#pragma unroll
    for (int r = 1; r < 16; ++r) pm = fmaxf(pm, P0[r]);
#pragma unroll
    for (int r = 0; r < 16; ++r) pm = fmaxf(pm, P1[r]);
    pm = fmaxf(pm, __shfl_xor(pm, 32));

    if (!__all(pm <= m + 8.f)) {      // T13 defer-max
      const float mn = fmaxf(m, pm);
      const float scl = __builtin_amdgcn_exp2f((m - mn) * LOG2E);
      m = mn;
      lsum *= scl;
      Ssc[wid][l31] = scl;            // broadcast q-indexed scale
      f32x4 s0 = *(const f32x4*)&Ssc[wid][hi * 4];
      f32x4 s1 = *(const f32x4*)&Ssc[wid][8 + hi * 4];
      f32x4 s2 = *(const f32x4*)&Ssc[wid][16 + hi * 4];
      f32x4 s3 = *(const f32x4*)&Ssc[wid][24 + hi * 4];
#pragma unroll
      for (int r = 0; r < 16; ++r) {
        const float sv = (r < 4 ? s0[r & 3] : r < 8 ? s1[r & 3] : r < 12 ? s2[r & 3] : s3[r & 3]);
        o0[r] *= sv; o1[r] *= sv;
      }
    }

#pragma unroll
    for (int r = 0; r < 16; ++r) P0[r] = __builtin_amdgcn_exp2f((P0[r] - m) * LOG2E);
#pragma unroll
    for (int r = 0; r < 16; ++r) P1[r] = __builtin_amdgcn_exp2f((P1[r] - m) * LOG2E);

    float rs = 0.f;
#pragma unroll
    for (int r = 0; r < 16; ++r) rs += P0[r] + P1[r];
    rs += __shfl_xor(rs, 32);
    lsum += rs;

    // ---- T12: P -> bf16 A-fragments in-register ----
    bf16x8 pa[4];
#pragma unroll
    for (int s = 0; s < 2; ++s) {
      const f32x16& P = s ? P1 : P0;
      uint a0 = cvtpk(P[0], P[1]),  b0 = cvtpk(P[4], P[5]);
      uint a1 = cvtpk(P[2], P[3]),  b1 = cvtpk(P[6], P[7]);
      plswap(a0, b0); plswap(a1, b1);
      pa[2 * s] = __builtin_bit_cast(bf16x8, (u32x4){a0, a1, b0, b1});
      uint a2 = cvtpk(P[8], P[9]),   b2 = cvtpk(P[12], P[13]);
      uint a3 = cvtpk(P[10], P[11]), b3 = cvtpk(P[14], P[15]);
      plswap(a2, b2); plswap(a3, b3);
      pa[2 * s + 1] = __builtin_bit_cast(bf16x8, (u32x4){a2, a3, b2, b3});
    }

    // ---- PV: o[dtile] += sum_kk mfma32(pa[kk], Vfrag(dtile,kk)) ----
    __builtin_amdgcn_s_setprio(1);
#pragma unroll
    for (int kk = 0; kk < 4; ++kk) {
      bf16x8 v0f = *(const bf16x8*)(Vsh + swz(l31,      kk * 32 + hi * 16));
      bf16x8 v1f = *(const bf16x8*)(Vsh + swz(32 + l31, kk * 32 + hi * 16));
      o0 = mfma32(pa[kk], v0f, o0);
      o1 = mfma32(pa[kk], v1f, o1);
    }
    __builtin_amdgcn_s_setprio(0);

    if (t + 1 < 32) {
      __syncthreads();                 // all waves done reading tile t
      *(u16x8*)(Ksh + swz(si, sc4i * 32))      = kr0;
      *(u16x8*)(Ksh + swz(si, sc4i * 32 + 16)) = kr1;
      *(u16x8*)(Vsh + swz(si, sc4i * 32))      = vr0;
      *(u16x8*)(Vsh + swz(si, sc4i * 32 + 16)) = vr1;
      __syncthreads();                 // tile t+1 ready
    }
  }

  // epilogue: broadcast 1/l by q, write ctx[B,S,EMB] bf16
  Ssc[wid][l31] = 1.0f / lsum;
  f32x4 i0 = *(const f32x4*)&Ssc[wid][hi * 4];
  f32x4 i1 = *(const f32x4*)&Ssc[wid][8 + hi * 4];
  f32x4 i2 = *(const f32x4*)&Ssc[wid][16 + hi * 4];
  f32x4 i3 = *(const f32x4*)&Ssc[wid][24 + hi * 4];
  const int b = bh >> 4, h = bh & 15;
#pragma unroll
  for (int r = 0; r < 16; ++r) {
    const float inv = (r < 4 ? i0[r & 3] : r < 8 ? i1[r & 3] : r < 12 ? i2[r & 3] : i3[r & 3]);
    const int q = q0 + (r & 3) + 8 * (r >> 2) + 4 * hi;
    const size_t base = ((size_t)(b * 2048 + q)) * 1024 + h * 64;
    ctxb[base + l31]      = f2bf(o0[r] * inv);
    ctxb[base + 32 + l31] = f2bf(o1[r] * inv);
  }
}

// ---------------- output projection (unchanged, known-good) ----------------
__global__ __launch_bounds__(256) void out_gemm(const ushort* __restrict__ A16,
                                                const ushort* __restrict__ Wb,
                                                const float* __restrict__ bias,
                                                float* __restrict__ O) {
  __shared__ ushort Ash[128 * 32];
  __shared__ ushort Bsh[128 * 32];

  const int tid = threadIdx.x;
  const int lane = tid & 63, wid = tid >> 6;
  const int l15 = lane & 15, g = lane >> 4;
  const int wr = wid >> 1, wc = wid & 1;
  const int tm = blockIdx.x * 128, tn = blockIdx.y * 128;

  const f32x4 fz = {0.f, 0.f, 0.f, 0.f};
  f32x4 acc[4][4];
#pragma unroll
  for (int m = 0; m < 4; ++m)
#pragma unroll
    for (int n = 0; n < 4; ++n) acc[m][n] = fz;

  for (int kt = 0; kt < 1024; kt += 32) {
#pragma unroll
    for (int c = 0; c < 2; ++c) {
      const int chunk = wid * 2 + c;
      const int off = chunk * 1024 + lane * 16;
      const int row = off >> 6;
      const int ke = (off & 63) >> 1;
      gload16(Wb + (size_t)(tn + row) * 1024 + kt + ke, &Bsh[chunk * 512]);
      gload16(A16 + (size_t)(tm + row) * 1024 + kt + ke, &Ash[chunk * 512]);
    }
    __syncthreads();

    bf16x8 af[4], bfr[4];
#pragma unroll
    for (int m = 0; m < 4; ++m)
      af[m] = *(const bf16x8*)&Ash[(wr * 64 + m * 16 + l15) * 32 + g * 8];
#pragma unroll
    for (int n = 0; n < 4; ++n)
      bfr[n] = *(const bf16x8*)&Bsh[(wc * 64 + n * 16 + l15) * 32 + g * 8];
#pragma unroll
    for (int m = 0; m < 4; ++m)
#pragma unroll
      for (int n = 0; n < 4; ++n) acc[m][n] = mfma16(af[m], bfr[n], acc[m][n]);
    __syncthreads();
  }

#pragma unroll
  for (int n = 0; n < 4; ++n) {
    const int col = tn + wc * 64 + n * 16 + l15;
    const float bv = bias[col];
#pragma unroll
    for (int m = 0; m < 4; ++m) {
      const int row0 = tm + wr * 64 + m * 16 + g * 4;
#pragma unroll
      for (int r = 0; r < 4; ++r)
        O[(size_t)(row0 + r) * 1024 + col] = acc[m][n][r] + bv;
    }
  }
}

extern "C" void kernel_launch(void* const* d_in, const int* in_sizes, int n_in,
                              void* d_out, int out_size, void* d_ws, size_t ws_size,
                              hipStream_t stream) {
  const float* query = (const float*)d_in[0];
  const float* key_  = (const float*)d_in[1];
  const float* value = (const float*)d_in[2];
  const float* Wq = (const float*)d_in[3];
  const float* bq = (const float*)d_in[4];
  const float* Wk = (const float*)d_in[5];
  const float* bk = (const float*)d_in[6];
  const float* Wv = (const float*)d_in[7];
  const float* bv = (const float*)d_in[8];
  const float* Wo = (const float*)d_in[9];
  const float* bo = (const float*)d_in[10];

  ushort* ws = (ushort*)d_ws;
  ushort* Wqb = ws;
  ushort* Wkb = ws + (1u << 20);
  ushort* Wvb = ws + (2u << 20);
  ushort* Wob = ws + (3u << 20);
  ushort* Qb  = ws + (4u << 20);
  ushort* Kb  = Qb + (4u << 20);
  ushort* VTb = Kb + (4u << 20);
  ushort* ctx = VTb + (4u << 20);

  dim3 blk(256);
  cvt_f32_bf16<<<512, blk, 0, stream>>>(Wq, Wqb, 131072);
  cvt_f32_bf16<<<512, blk, 0, stream>>>(Wk, Wkb, 131072);
  cvt_f32_bf16<<<512, blk, 0, stream>>>(Wv, Wvb, 131072);
  cvt_f32_bf16<<<512, blk, 0, stream>>>(Wo, Wob, 131072);

  QKVArgs a;
  a.A0 = query; a.A1 = key_; a.A2 = value;
  a.W0 = Wqb;  a.W1 = Wkb;  a.W2 = Wvb;
  a.b0 = bq;   a.b1 = bk;   a.b2 = bv;
  a.Qo = Qb;   a.Ko = Kb;   a.Vo = VTb;
  qkv_gemm<<<dim3(32, 8, 3), blk, 0, stream>>>(a);

  attn_fwd<<<dim3(16, 32), blk, 0, stream>>>(Qb, Kb, VTb, ctx);

  out_gemm<<<dim3(32, 8), blk, 0, stream>>>(ctx, Wob, bo, (float*)d_out);
}

// Round 5
// 155.375 us; speedup vs baseline: 1.4776x; 1.1006x over previous
//
#include <hip/hip_runtime.h>
#include <stdint.h>

typedef __attribute__((ext_vector_type(8)))  __bf16 bf16x8;
typedef __attribute__((ext_vector_type(4)))  float  f32x4;
typedef __attribute__((ext_vector_type(16))) float  f32x16;
typedef __attribute__((ext_vector_type(8)))  ushort u16x8;
typedef __attribute__((ext_vector_type(4)))  ushort u16x4;
typedef __attribute__((ext_vector_type(4)))  uint   u32x4;

#define LOG2E 1.44269504088896f

__device__ __forceinline__ ushort f2bf(float f) {
  uint32_t u = __float_as_uint(f);
  u += 0x7fffu + ((u >> 16) & 1u);   // RNE
  return (ushort)(u >> 16);
}
__device__ __forceinline__ float bf2f(ushort h) {
  return __uint_as_float(((uint32_t)h) << 16);
}
__device__ __forceinline__ void gload16(const void* g, void* l) {
  __builtin_amdgcn_global_load_lds((const __attribute__((address_space(1))) void*)g,
                                   (__attribute__((address_space(3))) void*)l, 16, 0, 0);
}
__device__ __forceinline__ f32x4 mfma16(bf16x8 a, bf16x8 b, f32x4 c) {
  return __builtin_amdgcn_mfma_f32_16x16x32_bf16(a, b, c, 0, 0, 0);
}
__device__ __forceinline__ f32x16 mfma32(bf16x8 a, bf16x8 b, f32x16 c) {
  return __builtin_amdgcn_mfma_f32_32x32x16_bf16(a, b, c, 0, 0, 0);
}
// LDS XOR swizzle for 128B rows (m214 G4): byte ^= (row&7)<<4
__device__ __forceinline__ int swz(int row, int byteoff) {
  return row * 128 + (byteoff ^ ((row & 7) << 4));
}
__device__ __forceinline__ uint cvtpk(float lo, float hi) {
  uint w;
  asm("v_cvt_pk_bf16_f32 %0, %1, %2" : "=v"(w) : "v"(lo), "v"(hi));
  return w;
}
__device__ __forceinline__ void plswap(uint& a, uint& b) {
  asm("v_permlane32_swap_b32 %0, %1" : "+v"(a), "+v"(b));
}

// ---------------- fp32 -> bf16 (weights) ----------------
__global__ __launch_bounds__(256) void cvt_f32_bf16(const float* __restrict__ src,
                                                    ushort* __restrict__ dst, int n8) {
  int i = blockIdx.x * 256 + threadIdx.x;
  if (i >= n8) return;
  const f32x4* s = (const f32x4*)src;
  f32x4 a = s[2 * i], b = s[2 * i + 1];
  u16x8 o;
  o[0] = f2bf(a[0]); o[1] = f2bf(a[1]); o[2] = f2bf(a[2]); o[3] = f2bf(a[3]);
  o[4] = f2bf(b[0]); o[5] = f2bf(b[1]); o[6] = f2bf(b[2]); o[7] = f2bf(b[3]);
  ((u16x8*)dst)[i] = o;
}

// ---------------- QKV projection GEMM ----------------
// A staged fp32 via global_load_lds with pre-swizzled SOURCE addresses
// (m173 pattern: LDS linear, global chunk XOR-permuted), B bf16 likewise.
// A tile [128][32] f32 (128B rows, XOR (row&7) over 8x16B chunks);
// B tile [128][32] bf16 (64B rows, XOR ((row>>1)&3) over 4x16B chunks).
struct QKVArgs {
  const float* A0; const float* A1; const float* A2;
  const ushort* W0; const ushort* W1; const ushort* W2;
  const float* b0; const float* b1; const float* b2;
  ushort* Qo; ushort* Ko; ushort* Vo;
};

__global__ __launch_bounds__(256) void qkv_gemm(QKVArgs args) {
  __shared__ float  Afs[128 * 32];   // 16 KB
  __shared__ ushort Bsh[128 * 32];   // 8 KB

  const int z = blockIdx.z;
  const float*  A32  = z == 0 ? args.A0 : (z == 1 ? args.A1 : args.A2);
  const ushort* Wb   = z == 0 ? args.W0 : (z == 1 ? args.W1 : args.W2);
  const float*  bias = z == 0 ? args.b0 : (z == 1 ? args.b1 : args.b2);

  const int tid = threadIdx.x;
  const int lane = tid & 63, wid = tid >> 6;
  const int l15 = lane & 15, g = lane >> 4;
  const int wr = wid >> 1, wc = wid & 1;
  const int tm = blockIdx.x * 128, tn = blockIdx.y * 128;

  const f32x4 fz = {0.f, 0.f, 0.f, 0.f};
  f32x4 acc[4][4];
#pragma unroll
  for (int m = 0; m < 4; ++m)
#pragma unroll
    for (int n = 0; n < 4; ++n) acc[m][n] = fz;

  for (int kt = 0; kt < 1024; kt += 32) {
    // B: 8 chunks of 1KB; chunk covers 16 rows x 64B; src chunk XOR ((row>>1)&3)
#pragma unroll
    for (int c = 0; c < 2; ++c) {
      const int chunk = wid * 2 + c;
      const int row = chunk * 16 + (lane >> 2);
      const int c4 = lane & 3;
      gload16(Wb + (size_t)(tn + row) * 1024 + kt + 8 * (c4 ^ ((row >> 1) & 3)),
              &Bsh[chunk * 512]);
    }
    // A: 16 chunks of 1KB; chunk covers 8 rows x 128B; src chunk XOR (row&7)
#pragma unroll
    for (int c = 0; c < 4; ++c) {
      const int chunk = wid * 4 + c;
      const int row = chunk * 8 + (lane >> 3);
      const int c8 = lane & 7;
      gload16(A32 + (size_t)(tm + row) * 1024 + kt + 4 * (c8 ^ (row & 7)),
              &Afs[chunk * 256]);
    }
    __syncthreads();

    bf16x8 af[4], bfr[4];
#pragma unroll
    for (int m = 0; m < 4; ++m) {
      const int row = wr * 64 + m * 16 + l15;
      f32x4 a0 = *(const f32x4*)((const char*)Afs + row * 128 + (((2 * g)     ^ (row & 7)) * 16));
      f32x4 a1 = *(const f32x4*)((const char*)Afs + row * 128 + (((2 * g + 1) ^ (row & 7)) * 16));
      af[m] = __builtin_bit_cast(bf16x8,
              (u32x4){cvtpk(a0[0], a0[1]), cvtpk(a0[2], a0[3]),
                      cvtpk(a1[0], a1[1]), cvtpk(a1[2], a1[3])});
    }
#pragma unroll
    for (int n = 0; n < 4; ++n) {
      const int row = wc * 64 + n * 16 + l15;
      bfr[n] = *(const bf16x8*)((const char*)Bsh + row * 64 + ((g ^ ((row >> 1) & 3)) * 16));
    }
#pragma unroll
    for (int m = 0; m < 4; ++m)
#pragma unroll
      for (int n = 0; n < 4; ++n) acc[m][n] = mfma16(af[m], bfr[n], acc[m][n]);
    __syncthreads();
  }

  // epilogue (unchanged)
#pragma unroll
  for (int n = 0; n < 4; ++n) {
    const int col = tn + wc * 64 + n * 16 + l15;
    const float bv = bias[col];
    const int h = col >> 6, d = col & 63;
#pragma unroll
    for (int m = 0; m < 4; ++m) {
      const int row0 = tm + wr * 64 + m * 16 + g * 4;
      if (z == 2) {            // V^T : [B,H,Dh,S]
        const int b = row0 >> 11, s0 = row0 & 2047;
        u16x4 pk;
#pragma unroll
        for (int r = 0; r < 4; ++r) pk[r] = f2bf(acc[m][n][r] + bv);
        *(u16x4*)&args.Vo[((size_t)((b * 16 + h) * 64 + d)) * 2048 + s0] = pk;
      } else {                 // Q/K : [B,H,S,Dh]
        ushort* O = z ? args.Ko : args.Qo;
#pragma unroll
        for (int r = 0; r < 4; ++r) {
          const int row = row0 + r;
          const int b = row >> 11, s = row & 2047;
          O[((size_t)(b * 16 + h) * 2048 + s) * 64 + d] = f2bf(acc[m][n][r] + bv);
        }
      }
    }
  }
}

// ---------------- flash attention (unchanged from round 4, known-good) ----
__global__ __launch_bounds__(256) void attn_fwd(const ushort* __restrict__ Qb,
                                                const ushort* __restrict__ Kb,
                                                const ushort* __restrict__ VTb,
                                                ushort* __restrict__ ctxb) {
  __shared__ char Ksh[64 * 128];
  __shared__ char Vsh[64 * 128];
  __shared__ float Ssc[4][32];

  const int tid = threadIdx.x;
  const int lane = tid & 63, wid = tid >> 6;
  const int l31 = lane & 31, hi = lane >> 5;
  const int bh = blockIdx.y;
  const int q0 = blockIdx.x * 128 + wid * 32;

  const ushort* Qh = Qb + (size_t)bh * 2048 * 64;
  const ushort* Kh = Kb + (size_t)bh * 2048 * 64;
  const ushort* Vh = VTb + (size_t)bh * 64 * 2048;

  bf16x8 qf[4];
  {
    const ushort* qrow = Qh + (size_t)(q0 + l31) * 64;
#pragma unroll
    for (int dt = 0; dt < 4; ++dt) {
      u16x8 raw = *(const u16x8*)&qrow[dt * 16 + hi * 8];
      u16x8 sc;
#pragma unroll
      for (int j = 0; j < 8; ++j) sc[j] = f2bf(bf2f(raw[j]) * 0.125f);
      qf[dt] = __builtin_bit_cast(bf16x8, sc);
    }
  }

  f32x16 o0 = {}, o1 = {};
  float m = -1e30f, lsum = 0.f;

  const int si = tid >> 2, sc4i = tid & 3;
  const ushort* kg = &Kh[(size_t)si * 64 + sc4i * 16];
  const ushort* vg = &Vh[(size_t)si * 2048 + sc4i * 16];

  u16x8 kr0, kr1, vr0, vr1;
  kr0 = *(const u16x8*)kg;  kr1 = *(const u16x8*)(kg + 8);
  vr0 = *(const u16x8*)vg;  vr1 = *(const u16x8*)(vg + 8);
  *(u16x8*)(Ksh + swz(si, sc4i * 32))      = kr0;
  *(u16x8*)(Ksh + swz(si, sc4i * 32 + 16)) = kr1;
  *(u16x8*)(Vsh + swz(si, sc4i * 32))      = vr0;
  *(u16x8*)(Vsh + swz(si, sc4i * 32 + 16)) = vr1;
  __syncthreads();

  for (int t = 0; t < 32; ++t) {
    if (t + 1 < 32) {
      const int kt2 = (t + 1) * 64;
      kr0 = *(const u16x8*)(kg + (size_t)kt2 * 64);
      kr1 = *(const u16x8*)(kg + (size_t)kt2 * 64 + 8);
      vr0 = *(const u16x8*)(vg + kt2);
      vr1 = *(const u16x8*)(vg + kt2 + 8);
    }

    f32x16 P0 = {}, P1 = {};
    __builtin_amdgcn_s_setprio(1);
#pragma unroll
    for (int dt = 0; dt < 4; ++dt) {
      bf16x8 kf0 = *(const bf16x8*)(Ksh + swz(l31,      dt * 32 + hi * 16));
      bf16x8 kf1 = *(const bf16x8*)(Ksh + swz(32 + l31, dt * 32 + hi * 16));
      P0 = mfma32(kf0, qf[dt], P0);
      P1 = mfma32(kf1, qf[dt], P1);
    }
    __builtin_amdgcn_s_setprio(0);

    float pm = P0[0];
#pragma unroll
    for (int r = 1; r < 16; ++r) pm = fmaxf(pm, P0[r]);
#pragma unroll
    for (int r = 0; r < 16; ++r) pm = fmaxf(pm, P1[r]);
    pm = fmaxf(pm, __shfl_xor(pm, 32));

    if (!__all(pm <= m + 8.f)) {
      const float mn = fmaxf(m, pm);
      const float scl = __builtin_amdgcn_exp2f((m - mn) * LOG2E);
      m = mn;
      lsum *= scl;
      Ssc[wid][l31] = scl;
      f32x4 s0 = *(const f32x4*)&Ssc[wid][hi * 4];
      f32x4 s1 = *(const f32x4*)&Ssc[wid][8 + hi * 4];
      f32x4 s2 = *(const f32x4*)&Ssc[wid][16 + hi * 4];
      f32x4 s3 = *(const f32x4*)&Ssc[wid][24 + hi * 4];
#pragma unroll
      for (int r = 0; r < 16; ++r) {
        const float sv = (r < 4 ? s0[r & 3] : r < 8 ? s1[r & 3] : r < 12 ? s2[r & 3] : s3[r & 3]);
        o0[r] *= sv; o1[r] *= sv;
      }
    }

#pragma unroll
    for (int r = 0; r < 16; ++r) P0[r] = __builtin_amdgcn_exp2f((P0[r] - m) * LOG2E);
#pragma unroll
    for (int r = 0; r < 16; ++r) P1[r] = __builtin_amdgcn_exp2f((P1[r] - m) * LOG2E);

    float rs = 0.f;
#pragma unroll
    for (int r = 0; r < 16; ++r) rs += P0[r] + P1[r];
    rs += __shfl_xor(rs, 32);
    lsum += rs;

    bf16x8 pa[4];
#pragma unroll
    for (int s = 0; s < 2; ++s) {
      const f32x16& P = s ? P1 : P0;
      uint a0 = cvtpk(P[0], P[1]),  b0 = cvtpk(P[4], P[5]);
      uint a1 = cvtpk(P[2], P[3]),  b1 = cvtpk(P[6], P[7]);
      plswap(a0, b0); plswap(a1, b1);
      pa[2 * s] = __builtin_bit_cast(bf16x8, (u32x4){a0, a1, b0, b1});
      uint a2 = cvtpk(P[8], P[9]),   b2 = cvtpk(P[12], P[13]);
      uint a3 = cvtpk(P[10], P[11]), b3 = cvtpk(P[14], P[15]);
      plswap(a2, b2); plswap(a3, b3);
      pa[2 * s + 1] = __builtin_bit_cast(bf16x8, (u32x4){a2, a3, b2, b3});
    }

    __builtin_amdgcn_s_setprio(1);
#pragma unroll
    for (int kk = 0; kk < 4; ++kk) {
      bf16x8 v0f = *(const bf16x8*)(Vsh + swz(l31,      kk * 32 + hi * 16));
      bf16x8 v1f = *(const bf16x8*)(Vsh + swz(32 + l31, kk * 32 + hi * 16));
      o0 = mfma32(pa[kk], v0f, o0);
      o1 = mfma32(pa[kk], v1f, o1);
    }
    __builtin_amdgcn_s_setprio(0);

    if (t + 1 < 32) {
      __syncthreads();
      *(u16x8*)(Ksh + swz(si, sc4i * 32))      = kr0;
      *(u16x8*)(Ksh + swz(si, sc4i * 32 + 16)) = kr1;
      *(u16x8*)(Vsh + swz(si, sc4i * 32))      = vr0;
      *(u16x8*)(Vsh + swz(si, sc4i * 32 + 16)) = vr1;
      __syncthreads();
    }
  }

  Ssc[wid][l31] = 1.0f / lsum;
  f32x4 i0 = *(const f32x4*)&Ssc[wid][hi * 4];
  f32x4 i1 = *(const f32x4*)&Ssc[wid][8 + hi * 4];
  f32x4 i2 = *(const f32x4*)&Ssc[wid][16 + hi * 4];
  f32x4 i3 = *(const f32x4*)&Ssc[wid][24 + hi * 4];
  const int b = bh >> 4, h = bh & 15;
#pragma unroll
  for (int r = 0; r < 16; ++r) {
    const float inv = (r < 4 ? i0[r & 3] : r < 8 ? i1[r & 3] : r < 12 ? i2[r & 3] : i3[r & 3]);
    const int q = q0 + (r & 3) + 8 * (r >> 2) + 4 * hi;
    const size_t base = ((size_t)(b * 2048 + q)) * 1024 + h * 64;
    ctxb[base + l31]      = f2bf(o0[r] * inv);
    ctxb[base + 32 + l31] = f2bf(o1[r] * inv);
  }
}

// ---------------- output projection (unchanged, known-good) ----------------
__global__ __launch_bounds__(256) void out_gemm(const ushort* __restrict__ A16,
                                                const ushort* __restrict__ Wb,
                                                const float* __restrict__ bias,
                                                float* __restrict__ O) {
  __shared__ ushort Ash[128 * 32];
  __shared__ ushort Bsh[128 * 32];

  const int tid = threadIdx.x;
  const int lane = tid & 63, wid = tid >> 6;
  const int l15 = lane & 15, g = lane >> 4;
  const int wr = wid >> 1, wc = wid & 1;
  const int tm = blockIdx.x * 128, tn = blockIdx.y * 128;

  const f32x4 fz = {0.f, 0.f, 0.f, 0.f};
  f32x4 acc[4][4];
#pragma unroll
  for (int m = 0; m < 4; ++m)
#pragma unroll
    for (int n = 0; n < 4; ++n) acc[m][n] = fz;

  for (int kt = 0; kt < 1024; kt += 32) {
#pragma unroll
    for (int c = 0; c < 2; ++c) {
      const int chunk = wid * 2 + c;
      const int off = chunk * 1024 + lane * 16;
      const int row = off >> 6;
      const int ke = (off & 63) >> 1;
      gload16(Wb + (size_t)(tn + row) * 1024 + kt + ke, &Bsh[chunk * 512]);
      gload16(A16 + (size_t)(tm + row) * 1024 + kt + ke, &Ash[chunk * 512]);
    }
    __syncthreads();

    bf16x8 af[4], bfr[4];
#pragma unroll
    for (int m = 0; m < 4; ++m)
      af[m] = *(const bf16x8*)&Ash[(wr * 64 + m * 16 + l15) * 32 + g * 8];
#pragma unroll
    for (int n = 0; n < 4; ++n)
      bfr[n] = *(const bf16x8*)&Bsh[(wc * 64 + n * 16 + l15) * 32 + g * 8];
#pragma unroll
    for (int m = 0; m < 4; ++m)
#pragma unroll
      for (int n = 0; n < 4; ++n) acc[m][n] = mfma16(af[m], bfr[n], acc[m][n]);
    __syncthreads();
  }

#pragma unroll
  for (int n = 0; n < 4; ++n) {
    const int col = tn + wc * 64 + n * 16 + l15;
    const float bv = bias[col];
#pragma unroll
    for (int m = 0; m < 4; ++m) {
      const int row0 = tm + wr * 64 + m * 16 + g * 4;
#pragma unroll
      for (int r = 0; r < 4; ++r)
        O[(size_t)(row0 + r) * 1024 + col] = acc[m][n][r] + bv;
    }
  }
}

extern "C" void kernel_launch(void* const* d_in, const int* in_sizes, int n_in,
                              void* d_out, int out_size, void* d_ws, size_t ws_size,
                              hipStream_t stream) {
  const float* query = (const float*)d_in[0];
  const float* key_  = (const float*)d_in[1];
  const float* value = (const float*)d_in[2];
  const float* Wq = (const float*)d_in[3];
  const float* bq = (const float*)d_in[4];
  const float* Wk = (const float*)d_in[5];
  const float* bk = (const float*)d_in[6];
  const float* Wv = (const float*)d_in[7];
  const float* bv = (const float*)d_in[8];
  const float* Wo = (const float*)d_in[9];
  const float* bo = (const float*)d_in[10];

  ushort* ws = (ushort*)d_ws;
  ushort* Wqb = ws;
  ushort* Wkb = ws + (1u << 20);
  ushort* Wvb = ws + (2u << 20);
  ushort* Wob = ws + (3u << 20);
  ushort* Qb  = ws + (4u << 20);
  ushort* Kb  = Qb + (4u << 20);
  ushort* VTb = Kb + (4u << 20);
  ushort* ctx = VTb + (4u << 20);

  dim3 blk(256);
  cvt_f32_bf16<<<512, blk, 0, stream>>>(Wq, Wqb, 131072);
  cvt_f32_bf16<<<512, blk, 0, stream>>>(Wk, Wkb, 131072);
  cvt_f32_bf16<<<512, blk, 0, stream>>>(Wv, Wvb, 131072);
  cvt_f32_bf16<<<512, blk, 0, stream>>>(Wo, Wob, 131072);

  QKVArgs a;
  a.A0 = query; a.A1 = key_; a.A2 = value;
  a.W0 = Wqb;  a.W1 = Wkb;  a.W2 = Wvb;
  a.b0 = bq;   a.b1 = bk;   a.b2 = bv;
  a.Qo = Qb;   a.Ko = Kb;   a.Vo = VTb;
  qkv_gemm<<<dim3(32, 8, 3), blk, 0, stream>>>(a);

  attn_fwd<<<dim3(16, 32), blk, 0, stream>>>(Qb, Kb, VTb, ctx);

  out_gemm<<<dim3(32, 8), blk, 0, stream>>>(ctx, Wob, bo, (float*)d_out);
}

// Round 6
// 142.216 us; speedup vs baseline: 1.6143x; 1.0925x over previous
//
#include <hip/hip_runtime.h>
#include <stdint.h>

typedef __attribute__((ext_vector_type(8)))  __bf16 bf16x8;
typedef __attribute__((ext_vector_type(4)))  float  f32x4;
typedef __attribute__((ext_vector_type(16))) float  f32x16;
typedef __attribute__((ext_vector_type(8)))  ushort u16x8;
typedef __attribute__((ext_vector_type(4)))  ushort u16x4;
typedef __attribute__((ext_vector_type(4)))  uint   u32x4;

#define LOG2E 1.44269504088896f

__device__ __forceinline__ ushort f2bf(float f) {
  uint32_t u = __float_as_uint(f);
  u += 0x7fffu + ((u >> 16) & 1u);   // RNE
  return (ushort)(u >> 16);
}
__device__ __forceinline__ float bf2f(ushort h) {
  return __uint_as_float(((uint32_t)h) << 16);
}
__device__ __forceinline__ void gload16(const void* g, void* l) {
  __builtin_amdgcn_global_load_lds((const __attribute__((address_space(1))) void*)g,
                                   (__attribute__((address_space(3))) void*)l, 16, 0, 0);
}
__device__ __forceinline__ f32x4 mfma16(bf16x8 a, bf16x8 b, f32x4 c) {
  return __builtin_amdgcn_mfma_f32_16x16x32_bf16(a, b, c, 0, 0, 0);
}
__device__ __forceinline__ f32x16 mfma32(bf16x8 a, bf16x8 b, f32x16 c) {
  return __builtin_amdgcn_mfma_f32_32x32x16_bf16(a, b, c, 0, 0, 0);
}
// LDS XOR swizzle for 128B rows (m214 G4): byte ^= (row&7)<<4
__device__ __forceinline__ int swz(int row, int byteoff) {
  return row * 128 + (byteoff ^ ((row & 7) << 4));
}
__device__ __forceinline__ uint cvtpk(float lo, float hi) {
  uint w;
  asm("v_cvt_pk_bf16_f32 %0, %1, %2" : "=v"(w) : "v"(lo), "v"(hi));
  return w;
}
__device__ __forceinline__ void plswap(uint& a, uint& b) {
  asm("v_permlane32_swap_b32 %0, %1" : "+v"(a), "+v"(b));
}

// ---------------- batched fp32 -> bf16 (weights + activations), ONE launch ----
// segs 0-3: weights (1M elems, 512 blocks each); segs 4-6: acts (4M elems, 2048 each)
struct CvtArgs { const float* src[7]; ushort* dst[7]; };

__global__ __launch_bounds__(256) void cvt_all(CvtArgs a) {
  const int bid = blockIdx.x;
  int seg, base;
  if (bid < 2048) { seg = bid >> 9;              base = bid & 511; }
  else            { seg = 4 + ((bid - 2048) >> 11); base = (bid - 2048) & 2047; }
  const int i = base * 256 + threadIdx.x;   // n8 index
  const f32x4* s = (const f32x4*)a.src[seg];
  f32x4 x = s[2 * i], y = s[2 * i + 1];
  u16x8 o;
  o[0] = f2bf(x[0]); o[1] = f2bf(x[1]); o[2] = f2bf(x[2]); o[3] = f2bf(x[3]);
  o[4] = f2bf(y[0]); o[5] = f2bf(y[1]); o[6] = f2bf(y[2]); o[7] = f2bf(y[3]);
  ((u16x8*)a.dst[seg])[i] = o;
}

// ---------------- QKV projection GEMM: pure bf16, m97 structure ----------------
// out = X[4096,1024](bf16) @ W^T(bf16) + bias ; 128x128 tile, BK=32, 4 waves 2x2.
// Both operands staged via linear global_load_lds (no VALU in staging path).
// z==0/1 -> Q/K layout [B,H,S,Dh]; z==2 -> V transposed [B,H,Dh,S].
struct QKVArgs {
  const ushort* A0; const ushort* A1; const ushort* A2;
  const ushort* W0; const ushort* W1; const ushort* W2;
  const float* b0; const float* b1; const float* b2;
  ushort* Qo; ushort* Ko; ushort* Vo;
};

__global__ __launch_bounds__(256) void qkv_gemm(QKVArgs args) {
  __shared__ ushort Ash[128 * 32];
  __shared__ ushort Bsh[128 * 32];

  const int z = blockIdx.z;
  const ushort* Ab   = z == 0 ? args.A0 : (z == 1 ? args.A1 : args.A2);
  const ushort* Wb   = z == 0 ? args.W0 : (z == 1 ? args.W1 : args.W2);
  const float*  bias = z == 0 ? args.b0 : (z == 1 ? args.b1 : args.b2);

  const int tid = threadIdx.x;
  const int lane = tid & 63, wid = tid >> 6;
  const int l15 = lane & 15, g = lane >> 4;
  const int wr = wid >> 1, wc = wid & 1;
  const int tm = blockIdx.x * 128, tn = blockIdx.y * 128;

  const f32x4 fz = {0.f, 0.f, 0.f, 0.f};
  f32x4 acc[4][4];
#pragma unroll
  for (int m = 0; m < 4; ++m)
#pragma unroll
    for (int n = 0; n < 4; ++n) acc[m][n] = fz;

  for (int kt = 0; kt < 1024; kt += 32) {
#pragma unroll
    for (int c = 0; c < 2; ++c) {
      const int chunk = wid * 2 + c;
      const int off = chunk * 1024 + lane * 16;
      const int row = off >> 6;
      const int ke = (off & 63) >> 1;
      gload16(Wb + (size_t)(tn + row) * 1024 + kt + ke, &Bsh[chunk * 512]);
      gload16(Ab + (size_t)(tm + row) * 1024 + kt + ke, &Ash[chunk * 512]);
    }
    __syncthreads();

    bf16x8 af[4], bfr[4];
#pragma unroll
    for (int m = 0; m < 4; ++m)
      af[m] = *(const bf16x8*)&Ash[(wr * 64 + m * 16 + l15) * 32 + g * 8];
#pragma unroll
    for (int n = 0; n < 4; ++n)
      bfr[n] = *(const bf16x8*)&Bsh[(wc * 64 + n * 16 + l15) * 32 + g * 8];
#pragma unroll
    for (int m = 0; m < 4; ++m)
#pragma unroll
      for (int n = 0; n < 4; ++n) acc[m][n] = mfma16(af[m], bfr[n], acc[m][n]);
    __syncthreads();
  }

  // epilogue (unchanged, known-good)
#pragma unroll
  for (int n = 0; n < 4; ++n) {
    const int col = tn + wc * 64 + n * 16 + l15;
    const float bv = bias[col];
    const int h = col >> 6, d = col & 63;
#pragma unroll
    for (int m = 0; m < 4; ++m) {
      const int row0 = tm + wr * 64 + m * 16 + g * 4;
      if (z == 2) {            // V^T : [B,H,Dh,S]
        const int b = row0 >> 11, s0 = row0 & 2047;
        u16x4 pk;
#pragma unroll
        for (int r = 0; r < 4; ++r) pk[r] = f2bf(acc[m][n][r] + bv);
        *(u16x4*)&args.Vo[((size_t)((b * 16 + h) * 64 + d)) * 2048 + s0] = pk;
      } else {                 // Q/K : [B,H,S,Dh]
        ushort* O = z ? args.Ko : args.Qo;
#pragma unroll
        for (int r = 0; r < 4; ++r) {
          const int row = row0 + r;
          const int b = row >> 11, s = row & 2047;
          O[((size_t)(b * 16 + h) * 2048 + s) * 64 + d] = f2bf(acc[m][n][r] + bv);
        }
      }
    }
  }
}

// ---------------- flash attention (unchanged, known-good) ----
__global__ __launch_bounds__(256) void attn_fwd(const ushort* __restrict__ Qb,
                                                const ushort* __restrict__ Kb,
                                                const ushort* __restrict__ VTb,
                                                ushort* __restrict__ ctxb) {
  __shared__ char Ksh[64 * 128];
  __shared__ char Vsh[64 * 128];
  __shared__ float Ssc[4][32];

  const int tid = threadIdx.x;
  const int lane = tid & 63, wid = tid >> 6;
  const int l31 = lane & 31, hi = lane >> 5;
  const int bh = blockIdx.y;
  const int q0 = blockIdx.x * 128 + wid * 32;

  const ushort* Qh = Qb + (size_t)bh * 2048 * 64;
  const ushort* Kh = Kb + (size_t)bh * 2048 * 64;
  const ushort* Vh = VTb + (size_t)bh * 64 * 2048;

  bf16x8 qf[4];
  {
    const ushort* qrow = Qh + (size_t)(q0 + l31) * 64;
#pragma unroll
    for (int dt = 0; dt < 4; ++dt) {
      u16x8 raw = *(const u16x8*)&qrow[dt * 16 + hi * 8];
      u16x8 sc;
#pragma unroll
      for (int j = 0; j < 8; ++j) sc[j] = f2bf(bf2f(raw[j]) * 0.125f);
      qf[dt] = __builtin_bit_cast(bf16x8, sc);
    }
  }

  f32x16 o0 = {}, o1 = {};
  float m = -1e30f, lsum = 0.f;

  const int si = tid >> 2, sc4i = tid & 3;
  const ushort* kg = &Kh[(size_t)si * 64 + sc4i * 16];
  const ushort* vg = &Vh[(size_t)si * 2048 + sc4i * 16];

  u16x8 kr0, kr1, vr0, vr1;
  kr0 = *(const u16x8*)kg;  kr1 = *(const u16x8*)(kg + 8);
  vr0 = *(const u16x8*)vg;  vr1 = *(const u16x8*)(vg + 8);
  *(u16x8*)(Ksh + swz(si, sc4i * 32))      = kr0;
  *(u16x8*)(Ksh + swz(si, sc4i * 32 + 16)) = kr1;
  *(u16x8*)(Vsh + swz(si, sc4i * 32))      = vr0;
  *(u16x8*)(Vsh + swz(si, sc4i * 32 + 16)) = vr1;
  __syncthreads();

  for (int t = 0; t < 32; ++t) {
    if (t + 1 < 32) {
      const int kt2 = (t + 1) * 64;
      kr0 = *(const u16x8*)(kg + (size_t)kt2 * 64);
      kr1 = *(const u16x8*)(kg + (size_t)kt2 * 64 + 8);
      vr0 = *(const u16x8*)(vg + kt2);
      vr1 = *(const u16x8*)(vg + kt2 + 8);
    }

    f32x16 P0 = {}, P1 = {};
    __builtin_amdgcn_s_setprio(1);
#pragma unroll
    for (int dt = 0; dt < 4; ++dt) {
      bf16x8 kf0 = *(const bf16x8*)(Ksh + swz(l31,      dt * 32 + hi * 16));
      bf16x8 kf1 = *(const bf16x8*)(Ksh + swz(32 + l31, dt * 32 + hi * 16));
      P0 = mfma32(kf0, qf[dt], P0);
      P1 = mfma32(kf1, qf[dt], P1);
    }
    __builtin_amdgcn_s_setprio(0);

    float pm = P0[0];
#pragma unroll
    for (int r = 1; r < 16; ++r) pm = fmaxf(pm, P0[r]);
#pragma unroll
    for (int r = 0; r < 16; ++r) pm = fmaxf(pm, P1[r]);
    pm = fmaxf(pm, __shfl_xor(pm, 32));

    if (!__all(pm <= m + 8.f)) {
      const float mn = fmaxf(m, pm);
      const float scl = __builtin_amdgcn_exp2f((m - mn) * LOG2E);
      m = mn;
      lsum *= scl;
      Ssc[wid][l31] = scl;
      f32x4 s0 = *(const f32x4*)&Ssc[wid][hi * 4];
      f32x4 s1 = *(const f32x4*)&Ssc[wid][8 + hi * 4];
      f32x4 s2 = *(const f32x4*)&Ssc[wid][16 + hi * 4];
      f32x4 s3 = *(const f32x4*)&Ssc[wid][24 + hi * 4];
#pragma unroll
      for (int r = 0; r < 16; ++r) {
        const float sv = (r < 4 ? s0[r & 3] : r < 8 ? s1[r & 3] : r < 12 ? s2[r & 3] : s3[r & 3]);
        o0[r] *= sv; o1[r] *= sv;
      }
    }

#pragma unroll
    for (int r = 0; r < 16; ++r) P0[r] = __builtin_amdgcn_exp2f((P0[r] - m) * LOG2E);
#pragma unroll
    for (int r = 0; r < 16; ++r) P1[r] = __builtin_amdgcn_exp2f((P1[r] - m) * LOG2E);

    float rs = 0.f;
#pragma unroll
    for (int r = 0; r < 16; ++r) rs += P0[r] + P1[r];
    rs += __shfl_xor(rs, 32);
    lsum += rs;

    bf16x8 pa[4];
#pragma unroll
    for (int s = 0; s < 2; ++s) {
      const f32x16& P = s ? P1 : P0;
      uint a0 = cvtpk(P[0], P[1]),  b0 = cvtpk(P[4], P[5]);
      uint a1 = cvtpk(P[2], P[3]),  b1 = cvtpk(P[6], P[7]);
      plswap(a0, b0); plswap(a1, b1);
      pa[2 * s] = __builtin_bit_cast(bf16x8, (u32x4){a0, a1, b0, b1});
      uint a2 = cvtpk(P[8], P[9]),   b2 = cvtpk(P[12], P[13]);
      uint a3 = cvtpk(P[10], P[11]), b3 = cvtpk(P[14], P[15]);
      plswap(a2, b2); plswap(a3, b3);
      pa[2 * s + 1] = __builtin_bit_cast(bf16x8, (u32x4){a2, a3, b2, b3});
    }

    __builtin_amdgcn_s_setprio(1);
#pragma unroll
    for (int kk = 0; kk < 4; ++kk) {
      bf16x8 v0f = *(const bf16x8*)(Vsh + swz(l31,      kk * 32 + hi * 16));
      bf16x8 v1f = *(const bf16x8*)(Vsh + swz(32 + l31, kk * 32 + hi * 16));
      o0 = mfma32(pa[kk], v0f, o0);
      o1 = mfma32(pa[kk], v1f, o1);
    }
    __builtin_amdgcn_s_setprio(0);

    if (t + 1 < 32) {
      __syncthreads();
      *(u16x8*)(Ksh + swz(si, sc4i * 32))      = kr0;
      *(u16x8*)(Ksh + swz(si, sc4i * 32 + 16)) = kr1;
      *(u16x8*)(Vsh + swz(si, sc4i * 32))      = vr0;
      *(u16x8*)(Vsh + swz(si, sc4i * 32 + 16)) = vr1;
      __syncthreads();
    }
  }

  Ssc[wid][l31] = 1.0f / lsum;
  f32x4 i0 = *(const f32x4*)&Ssc[wid][hi * 4];
  f32x4 i1 = *(const f32x4*)&Ssc[wid][8 + hi * 4];
  f32x4 i2 = *(const f32x4*)&Ssc[wid][16 + hi * 4];
  f32x4 i3 = *(const f32x4*)&Ssc[wid][24 + hi * 4];
  const int b = bh >> 4, h = bh & 15;
#pragma unroll
  for (int r = 0; r < 16; ++r) {
    const float inv = (r < 4 ? i0[r & 3] : r < 8 ? i1[r & 3] : r < 12 ? i2[r & 3] : i3[r & 3]);
    const int q = q0 + (r & 3) + 8 * (r >> 2) + 4 * hi;
    const size_t base = ((size_t)(b * 2048 + q)) * 1024 + h * 64;
    ctxb[base + l31]      = f2bf(o0[r] * inv);
    ctxb[base + 32 + l31] = f2bf(o1[r] * inv);
  }
}

// ---------------- output projection: 64x128 tile (2 blocks/CU) ----------------
__global__ __launch_bounds__(256) void out_gemm(const ushort* __restrict__ A16,
                                                const ushort* __restrict__ Wb,
                                                const float* __restrict__ bias,
                                                float* __restrict__ O) {
  __shared__ ushort Ash[64 * 32];    // 4 KB, 4 chunks
  __shared__ ushort Bsh[128 * 32];   // 8 KB, 8 chunks

  const int tid = threadIdx.x;
  const int lane = tid & 63, wid = tid >> 6;
  const int l15 = lane & 15, g = lane >> 4;
  const int wr = wid >> 1, wc = wid & 1;
  const int tm = blockIdx.x * 64, tn = blockIdx.y * 128;

  const f32x4 fz = {0.f, 0.f, 0.f, 0.f};
  f32x4 acc[2][4];
#pragma unroll
  for (int m = 0; m < 2; ++m)
#pragma unroll
    for (int n = 0; n < 4; ++n) acc[m][n] = fz;

  for (int kt = 0; kt < 1024; kt += 32) {
#pragma unroll
    for (int c = 0; c < 2; ++c) {
      const int chunk = wid * 2 + c;
      const int off = chunk * 1024 + lane * 16;
      const int row = off >> 6;
      const int ke = (off & 63) >> 1;
      gload16(Wb + (size_t)(tn + row) * 1024 + kt + ke, &Bsh[chunk * 512]);
    }
    {
      const int off = wid * 1024 + lane * 16;
      const int row = off >> 6;
      const int ke = (off & 63) >> 1;
      gload16(A16 + (size_t)(tm + row) * 1024 + kt + ke, &Ash[wid * 512]);
    }
    __syncthreads();

    bf16x8 af[2], bfr[4];
#pragma unroll
    for (int m = 0; m < 2; ++m)
      af[m] = *(const bf16x8*)&Ash[(wr * 32 + m * 16 + l15) * 32 + g * 8];
#pragma unroll
    for (int n = 0; n < 4; ++n)
      bfr[n] = *(const bf16x8*)&Bsh[(wc * 64 + n * 16 + l15) * 32 + g * 8];
#pragma unroll
    for (int m = 0; m < 2; ++m)
#pragma unroll
      for (int n = 0; n < 4; ++n) acc[m][n] = mfma16(af[m], bfr[n], acc[m][n]);
    __syncthreads();
  }

#pragma unroll
  for (int n = 0; n < 4; ++n) {
    const int col = tn + wc * 64 + n * 16 + l15;
    const float bv = bias[col];
#pragma unroll
    for (int m = 0; m < 2; ++m) {
      const int row0 = tm + wr * 32 + m * 16 + g * 4;
#pragma unroll
      for (int r = 0; r < 4; ++r)
        O[(size_t)(row0 + r) * 1024 + col] = acc[m][n][r] + bv;
    }
  }
}

extern "C" void kernel_launch(void* const* d_in, const int* in_sizes, int n_in,
                              void* d_out, int out_size, void* d_ws, size_t ws_size,
                              hipStream_t stream) {
  const float* query = (const float*)d_in[0];
  const float* key_  = (const float*)d_in[1];
  const float* value = (const float*)d_in[2];
  const float* Wq = (const float*)d_in[3];
  const float* bq = (const float*)d_in[4];
  const float* Wk = (const float*)d_in[5];
  const float* bk = (const float*)d_in[6];
  const float* Wv = (const float*)d_in[7];
  const float* bv = (const float*)d_in[8];
  const float* Wo = (const float*)d_in[9];
  const float* bo = (const float*)d_in[10];

  ushort* ws = (ushort*)d_ws;
  ushort* Wqb = ws;                       // 1M elems each
  ushort* Wkb = ws + (1u << 20);
  ushort* Wvb = ws + (2u << 20);
  ushort* Wob = ws + (3u << 20);
  ushort* Qb  = ws + (4u << 20);          // 4M elems each
  ushort* Kb  = Qb + (4u << 20);
  ushort* VTb = Kb + (4u << 20);
  ushort* ctx = VTb + (4u << 20);         // 4M elems; doubles as Xq scratch
  // bf16 activations: Xq aliases ctx (dead until attn); Xk/Xv live in d_out
  // (32 MB, dead until out_gemm, fully overwritten by it each call).
  ushort* Xqb = ctx;
  ushort* Xkb = (ushort*)d_out;
  ushort* Xvb = (ushort*)d_out + (4u << 20);

  dim3 blk(256);

  CvtArgs ca;
  ca.src[0] = Wq;    ca.dst[0] = Wqb;
  ca.src[1] = Wk;    ca.dst[1] = Wkb;
  ca.src[2] = Wv;    ca.dst[2] = Wvb;
  ca.src[3] = Wo;    ca.dst[3] = Wob;
  ca.src[4] = query; ca.dst[4] = Xqb;
  ca.src[5] = key_;  ca.dst[5] = Xkb;
  ca.src[6] = value; ca.dst[6] = Xvb;
  cvt_all<<<8192, blk, 0, stream>>>(ca);

  QKVArgs a;
  a.A0 = Xqb;  a.A1 = Xkb;  a.A2 = Xvb;
  a.W0 = Wqb;  a.W1 = Wkb;  a.W2 = Wvb;
  a.b0 = bq;   a.b1 = bk;   a.b2 = bv;
  a.Qo = Qb;   a.Ko = Kb;   a.Vo = VTb;
  qkv_gemm<<<dim3(32, 8, 3), blk, 0, stream>>>(a);

  attn_fwd<<<dim3(16, 32), blk, 0, stream>>>(Qb, Kb, VTb, ctx);

  out_gemm<<<dim3(64, 8), blk, 0, stream>>>(ctx, Wob, bo, (float*)d_out);
}

// Round 10
// 140.589 us; speedup vs baseline: 1.6330x; 1.0116x over previous
//
#include <hip/hip_runtime.h>
#include <stdint.h>

typedef __attribute__((ext_vector_type(8)))  __bf16 bf16x8;
typedef __attribute__((ext_vector_type(4)))  float  f32x4;
typedef __attribute__((ext_vector_type(16))) float  f32x16;
typedef __attribute__((ext_vector_type(8)))  ushort u16x8;
typedef __attribute__((ext_vector_type(4)))  ushort u16x4;
typedef __attribute__((ext_vector_type(4)))  uint   u32x4;

#define LOG2E 1.44269504088896f

__device__ __forceinline__ ushort f2bf(float f) {
  uint32_t u = __float_as_uint(f);
  u += 0x7fffu + ((u >> 16) & 1u);   // RNE
  return (ushort)(u >> 16);
}
__device__ __forceinline__ float bf2f(ushort h) {
  return __uint_as_float(((uint32_t)h) << 16);
}
__device__ __forceinline__ void gload16(const void* g, void* l) {
  __builtin_amdgcn_global_load_lds((const __attribute__((address_space(1))) void*)g,
                                   (__attribute__((address_space(3))) void*)l, 16, 0, 0);
}
__device__ __forceinline__ f32x4 mfma16(bf16x8 a, bf16x8 b, f32x4 c) {
  return __builtin_amdgcn_mfma_f32_16x16x32_bf16(a, b, c, 0, 0, 0);
}
__device__ __forceinline__ f32x16 mfma32(bf16x8 a, bf16x8 b, f32x16 c) {
  return __builtin_amdgcn_mfma_f32_32x32x16_bf16(a, b, c, 0, 0, 0);
}
// LDS XOR swizzle for 128B rows (m214 G4): byte ^= (row&7)<<4
__device__ __forceinline__ int swz(int row, int byteoff) {
  return row * 128 + (byteoff ^ ((row & 7) << 4));
}
__device__ __forceinline__ uint cvtpk(float lo, float hi) {
  uint w;
  asm("v_cvt_pk_bf16_f32 %0, %1, %2" : "=v"(w) : "v"(lo), "v"(hi));
  return w;
}
__device__ __forceinline__ void plswap(uint& a, uint& b) {
  asm("v_permlane32_swap_b32 %0, %1" : "+v"(a), "+v"(b));
}
// NOTE (R7/R8 post-mortem): permlane-based cross-half merge helpers
// (mov+swap on a value copy) FAILED on hardware twice with ~6e-2 absmax
// despite passing paper analysis under either half-swap semantics.
// Cross-half merges must keep half-lane pairs (l, l^32) bit-identical;
// __shfl_xor(x,32) (ds_bpermute) is the validated way. Do not retry the
// permlane merge idiom without an isolated A/B probe.

// ---------------- batched fp32 -> bf16 (weights + activations), ONE launch ----
struct CvtArgs { const float* src[7]; ushort* dst[7]; };

__global__ __launch_bounds__(256) void cvt_all(CvtArgs a) {
  const int bid = blockIdx.x;
  int seg, base;
  if (bid < 2048) { seg = bid >> 9;              base = bid & 511; }
  else            { seg = 4 + ((bid - 2048) >> 11); base = (bid - 2048) & 2047; }
  const int i = base * 256 + threadIdx.x;   // n8 index
  const f32x4* s = (const f32x4*)a.src[seg];
  f32x4 x = s[2 * i], y = s[2 * i + 1];
  u16x8 o;
  o[0] = f2bf(x[0]); o[1] = f2bf(x[1]); o[2] = f2bf(x[2]); o[3] = f2bf(x[3]);
  o[4] = f2bf(y[0]); o[5] = f2bf(y[1]); o[6] = f2bf(y[2]); o[7] = f2bf(y[3]);
  ((u16x8*)a.dst[seg])[i] = o;
}

// ---------------- QKV projection GEMM: pure bf16, m97 structure ----------------
struct QKVArgs {
  const ushort* A0; const ushort* A1; const ushort* A2;
  const ushort* W0; const ushort* W1; const ushort* W2;
  const float* b0; const float* b1; const float* b2;
  ushort* Qo; ushort* Ko; ushort* Vo;
};

__global__ __launch_bounds__(256) void qkv_gemm(QKVArgs args) {
  __shared__ ushort Ash[128 * 32];
  __shared__ ushort Bsh[128 * 32];

  const int z = blockIdx.z;
  const ushort* Ab   = z == 0 ? args.A0 : (z == 1 ? args.A1 : args.A2);
  const ushort* Wb   = z == 0 ? args.W0 : (z == 1 ? args.W1 : args.W2);
  const float*  bias = z == 0 ? args.b0 : (z == 1 ? args.b1 : args.b2);

  const int tid = threadIdx.x;
  const int lane = tid & 63, wid = tid >> 6;
  const int l15 = lane & 15, g = lane >> 4;
  const int wr = wid >> 1, wc = wid & 1;
  const int tm = blockIdx.x * 128, tn = blockIdx.y * 128;

  const f32x4 fz = {0.f, 0.f, 0.f, 0.f};
  f32x4 acc[4][4];
#pragma unroll
  for (int m = 0; m < 4; ++m)
#pragma unroll
    for (int n = 0; n < 4; ++n) acc[m][n] = fz;

  for (int kt = 0; kt < 1024; kt += 32) {
#pragma unroll
    for (int c = 0; c < 2; ++c) {
      const int chunk = wid * 2 + c;
      const int off = chunk * 1024 + lane * 16;
      const int row = off >> 6;
      const int ke = (off & 63) >> 1;
      gload16(Wb + (size_t)(tn + row) * 1024 + kt + ke, &Bsh[chunk * 512]);
      gload16(Ab + (size_t)(tm + row) * 1024 + kt + ke, &Ash[chunk * 512]);
    }
    __syncthreads();

    bf16x8 af[4], bfr[4];
#pragma unroll
    for (int m = 0; m < 4; ++m)
      af[m] = *(const bf16x8*)&Ash[(wr * 64 + m * 16 + l15) * 32 + g * 8];
#pragma unroll
    for (int n = 0; n < 4; ++n)
      bfr[n] = *(const bf16x8*)&Bsh[(wc * 64 + n * 16 + l15) * 32 + g * 8];
#pragma unroll
    for (int m = 0; m < 4; ++m)
#pragma unroll
      for (int n = 0; n < 4; ++n) acc[m][n] = mfma16(af[m], bfr[n], acc[m][n]);
    __syncthreads();
  }

#pragma unroll
  for (int n = 0; n < 4; ++n) {
    const int col = tn + wc * 64 + n * 16 + l15;
    const float bv = bias[col];
    const int h = col >> 6, d = col & 63;
#pragma unroll
    for (int m = 0; m < 4; ++m) {
      const int row0 = tm + wr * 64 + m * 16 + g * 4;
      if (z == 2) {            // V^T : [B,H,Dh,S]
        const int b = row0 >> 11, s0 = row0 & 2047;
        u16x4 pk;
#pragma unroll
        for (int r = 0; r < 4; ++r) pk[r] = f2bf(acc[m][n][r] + bv);
        *(u16x4*)&args.Vo[((size_t)((b * 16 + h) * 64 + d)) * 2048 + s0] = pk;
      } else {                 // Q/K : [B,H,S,Dh]
        ushort* O = z ? args.Ko : args.Qo;
#pragma unroll
        for (int r = 0; r < 4; ++r) {
          const int row = row0 + r;
          const int b = row >> 11, s = row & 2047;
          O[((size_t)(b * 16 + h) * 2048 + s) * 64 + d] = f2bf(acc[m][n][r] + bv);
        }
      }
    }
  }
}

// ---------------- flash attention ----
// R6-validated structure; only exact-arithmetic trims kept from R7:
// max3 reduction tree (exact reassociation) + fma-folded exp argument.
// Cross-half merges via __shfl_xor (validated; see helper NOTE above).
__global__ __launch_bounds__(256) void attn_fwd(const ushort* __restrict__ Qb,
                                                const ushort* __restrict__ Kb,
                                                const ushort* __restrict__ VTb,
                                                ushort* __restrict__ ctxb) {
  __shared__ char Ksh[64 * 128];
  __shared__ char Vsh[64 * 128];
  __shared__ float Ssc[4][32];

  const int tid = threadIdx.x;
  const int lane = tid & 63, wid = tid >> 6;
  const int l31 = lane & 31, hi = lane >> 5;
  const int bh = blockIdx.y;
  const int q0 = blockIdx.x * 128 + wid * 32;

  const ushort* Qh = Qb + (size_t)bh * 2048 * 64;
  const ushort* Kh = Kb + (size_t)bh * 2048 * 64;
  const ushort* Vh = VTb + (size_t)bh * 64 * 2048;

  bf16x8 qf[4];
  {
    const ushort* qrow = Qh + (size_t)(q0 + l31) * 64;
#pragma unroll
    for (int dt = 0; dt < 4; ++dt) {
      u16x8 raw = *(const u16x8*)&qrow[dt * 16 + hi * 8];
      u16x8 sc;
#pragma unroll
      for (int j = 0; j < 8; ++j) sc[j] = f2bf(bf2f(raw[j]) * 0.125f);
      qf[dt] = __builtin_bit_cast(bf16x8, sc);
    }
  }

  f32x16 o0 = {}, o1 = {};
  float m = -1e30f, lsum = 0.f;

  const int si = tid >> 2, sc4i = tid & 3;
  const ushort* kg = &Kh[(size_t)si * 64 + sc4i * 16];
  const ushort* vg = &Vh[(size_t)si * 2048 + sc4i * 16];

  u16x8 kr0, kr1, vr0, vr1;
  kr0 = *(const u16x8*)kg;  kr1 = *(const u16x8*)(kg + 8);
  vr0 = *(const u16x8*)vg;  vr1 = *(const u16x8*)(vg + 8);
  *(u16x8*)(Ksh + swz(si, sc4i * 32))      = kr0;
  *(u16x8*)(Ksh + swz(si, sc4i * 32 + 16)) = kr1;
  *(u16x8*)(Vsh + swz(si, sc4i * 32))      = vr0;
  *(u16x8*)(Vsh + swz(si, sc4i * 32 + 16)) = vr1;
  __syncthreads();

  for (int t = 0; t < 32; ++t) {
    if (t + 1 < 32) {
      const int kt2 = (t + 1) * 64;
      kr0 = *(const u16x8*)(kg + (size_t)kt2 * 64);
      kr1 = *(const u16x8*)(kg + (size_t)kt2 * 64 + 8);
      vr0 = *(const u16x8*)(vg + kt2);
      vr1 = *(const u16x8*)(vg + kt2 + 8);
    }

    f32x16 P0 = {}, P1 = {};
    __builtin_amdgcn_s_setprio(1);
#pragma unroll
    for (int dt = 0; dt < 4; ++dt) {
      bf16x8 kf0 = *(const bf16x8*)(Ksh + swz(l31,      dt * 32 + hi * 16));
      bf16x8 kf1 = *(const bf16x8*)(Ksh + swz(32 + l31, dt * 32 + hi * 16));
      P0 = mfma32(kf0, qf[dt], P0);
      P1 = mfma32(kf1, qf[dt], P1);
    }
    __builtin_amdgcn_s_setprio(0);

    // local max via v_max3 chains (nested fmaxf folds to v_max3_f32; exact)
    float pm = fmaxf(P0[0], P1[0]);
#pragma unroll
    for (int r = 1; r + 1 < 16; r += 2) {
      pm = fmaxf(fmaxf(pm, P0[r]), P0[r + 1]);
      pm = fmaxf(fmaxf(pm, P1[r]), P1[r + 1]);
    }
    pm = fmaxf(fmaxf(pm, P0[15]), P1[15]);
    pm = fmaxf(pm, __shfl_xor(pm, 32));   // cross-half merge (validated path)

    if (!__all(pm <= m + 8.f)) {          // T13 defer-max
      const float mn = fmaxf(m, pm);
      const float scl = __builtin_amdgcn_exp2f((m - mn) * LOG2E);
      m = mn;
      lsum *= scl;
      Ssc[wid][l31] = scl;
      f32x4 s0 = *(const f32x4*)&Ssc[wid][hi * 4];
      f32x4 s1 = *(const f32x4*)&Ssc[wid][8 + hi * 4];
      f32x4 s2 = *(const f32x4*)&Ssc[wid][16 + hi * 4];
      f32x4 s3 = *(const f32x4*)&Ssc[wid][24 + hi * 4];
#pragma unroll
      for (int r = 0; r < 16; ++r) {
        const float sv = (r < 4 ? s0[r & 3] : r < 8 ? s1[r & 3] : r < 12 ? s2[r & 3] : s3[r & 3]);
        o0[r] *= sv; o1[r] *= sv;
      }
    }

    // P = exp2(fma(S, LOG2E, -m*LOG2E)) — one fma + one exp per element
    const float nml = -m * LOG2E;
#pragma unroll
    for (int r = 0; r < 16; ++r)
      P0[r] = __builtin_amdgcn_exp2f(__builtin_fmaf(P0[r], LOG2E, nml));
#pragma unroll
    for (int r = 0; r < 16; ++r)
      P1[r] = __builtin_amdgcn_exp2f(__builtin_fmaf(P1[r], LOG2E, nml));

    float rs = 0.f;
#pragma unroll
    for (int r = 0; r < 16; ++r) rs += P0[r] + P1[r];
    rs += __shfl_xor(rs, 32);             // cross-half merge (validated path)
    lsum += rs;

    bf16x8 pa[4];
#pragma unroll
    for (int s = 0; s < 2; ++s) {
      const f32x16& P = s ? P1 : P0;
      uint a0 = cvtpk(P[0], P[1]),  b0 = cvtpk(P[4], P[5]);
      uint a1 = cvtpk(P[2], P[3]),  b1 = cvtpk(P[6], P[7]);
      plswap(a0, b0); plswap(a1, b1);
      pa[2 * s] = __builtin_bit_cast(bf16x8, (u32x4){a0, a1, b0, b1});
      uint a2 = cvtpk(P[8], P[9]),   b2 = cvtpk(P[12], P[13]);
      uint a3 = cvtpk(P[10], P[11]), b3 = cvtpk(P[14], P[15]);
      plswap(a2, b2); plswap(a3, b3);
      pa[2 * s + 1] = __builtin_bit_cast(bf16x8, (u32x4){a2, a3, b2, b3});
    }

    __builtin_amdgcn_s_setprio(1);
#pragma unroll
    for (int kk = 0; kk < 4; ++kk) {
      bf16x8 v0f = *(const bf16x8*)(Vsh + swz(l31,      kk * 32 + hi * 16));
      bf16x8 v1f = *(const bf16x8*)(Vsh + swz(32 + l31, kk * 32 + hi * 16));
      o0 = mfma32(pa[kk], v0f, o0);
      o1 = mfma32(pa[kk], v1f, o1);
    }
    __builtin_amdgcn_s_setprio(0);

    if (t + 1 < 32) {
      __syncthreads();
      *(u16x8*)(Ksh + swz(si, sc4i * 32))      = kr0;
      *(u16x8*)(Ksh + swz(si, sc4i * 32 + 16)) = kr1;
      *(u16x8*)(Vsh + swz(si, sc4i * 32))      = vr0;
      *(u16x8*)(Vsh + swz(si, sc4i * 32 + 16)) = vr1;
      __syncthreads();
    }
  }

  Ssc[wid][l31] = 1.0f / lsum;
  f32x4 i0 = *(const f32x4*)&Ssc[wid][hi * 4];
  f32x4 i1 = *(const f32x4*)&Ssc[wid][8 + hi * 4];
  f32x4 i2 = *(const f32x4*)&Ssc[wid][16 + hi * 4];
  f32x4 i3 = *(const f32x4*)&Ssc[wid][24 + hi * 4];
  const int b = bh >> 4, h = bh & 15;
#pragma unroll
  for (int r = 0; r < 16; ++r) {
    const float inv = (r < 4 ? i0[r & 3] : r < 8 ? i1[r & 3] : r < 12 ? i2[r & 3] : i3[r & 3]);
    const int q = q0 + (r & 3) + 8 * (r >> 2) + 4 * hi;
    const size_t base = ((size_t)(b * 2048 + q)) * 1024 + h * 64;
    ctxb[base + l31]      = f2bf(o0[r] * inv);
    ctxb[base + 32 + l31] = f2bf(o1[r] * inv);
  }
}

// ---------------- output projection: 64x128 tile (2 blocks/CU) ----------------
__global__ __launch_bounds__(256) void out_gemm(const ushort* __restrict__ A16,
                                                const ushort* __restrict__ Wb,
                                                const float* __restrict__ bias,
                                                float* __restrict__ O) {
  __shared__ ushort Ash[64 * 32];
  __shared__ ushort Bsh[128 * 32];

  const int tid = threadIdx.x;
  const int lane = tid & 63, wid = tid >> 6;
  const int l15 = lane & 15, g = lane >> 4;
  const int wr = wid >> 1, wc = wid & 1;
  const int tm = blockIdx.x * 64, tn = blockIdx.y * 128;

  const f32x4 fz = {0.f, 0.f, 0.f, 0.f};
  f32x4 acc[2][4];
#pragma unroll
  for (int m = 0; m < 2; ++m)
#pragma unroll
    for (int n = 0; n < 4; ++n) acc[m][n] = fz;

  for (int kt = 0; kt < 1024; kt += 32) {
#pragma unroll
    for (int c = 0; c < 2; ++c) {
      const int chunk = wid * 2 + c;
      const int off = chunk * 1024 + lane * 16;
      const int row = off >> 6;
      const int ke = (off & 63) >> 1;
      gload16(Wb + (size_t)(tn + row) * 1024 + kt + ke, &Bsh[chunk * 512]);
    }
    {
      const int off = wid * 1024 + lane * 16;
      const int row = off >> 6;
      const int ke = (off & 63) >> 1;
      gload16(A16 + (size_t)(tm + row) * 1024 + kt + ke, &Ash[wid * 512]);
    }
    __syncthreads();

    bf16x8 af[2], bfr[4];
#pragma unroll
    for (int m = 0; m < 2; ++m)
      af[m] = *(const bf16x8*)&Ash[(wr * 32 + m * 16 + l15) * 32 + g * 8];
#pragma unroll
    for (int n = 0; n < 4; ++n)
      bfr[n] = *(const bf16x8*)&Bsh[(wc * 64 + n * 16 + l15) * 32 + g * 8];
#pragma unroll
    for (int m = 0; m < 2; ++m)
#pragma unroll
      for (int n = 0; n < 4; ++n) acc[m][n] = mfma16(af[m], bfr[n], acc[m][n]);
    __syncthreads();
  }

#pragma unroll
  for (int n = 0; n < 4; ++n) {
    const int col = tn + wc * 64 + n * 16 + l15;
    const float bv = bias[col];
#pragma unroll
    for (int m = 0; m < 2; ++m) {
      const int row0 = tm + wr * 32 + m * 16 + g * 4;
#pragma unroll
      for (int r = 0; r < 4; ++r)
        O[(size_t)(row0 + r) * 1024 + col] = acc[m][n][r] + bv;
    }
  }
}

extern "C" void kernel_launch(void* const* d_in, const int* in_sizes, int n_in,
                              void* d_out, int out_size, void* d_ws, size_t ws_size,
                              hipStream_t stream) {
  const float* query = (const float*)d_in[0];
  const float* key_  = (const float*)d_in[1];
  const float* value = (const float*)d_in[2];
  const float* Wq = (const float*)d_in[3];
  const float* bq = (const float*)d_in[4];
  const float* Wk = (const float*)d_in[5];
  const float* bk = (const float*)d_in[6];
  const float* Wv = (const float*)d_in[7];
  const float* bv = (const float*)d_in[8];
  const float* Wo = (const float*)d_in[9];
  const float* bo = (const float*)d_in[10];

  ushort* ws = (ushort*)d_ws;
  ushort* Wqb = ws;                       // 1M elems each
  ushort* Wkb = ws + (1u << 20);
  ushort* Wvb = ws + (2u << 20);
  ushort* Wob = ws + (3u << 20);
  ushort* Qb  = ws + (4u << 20);          // 4M elems each
  ushort* Kb  = Qb + (4u << 20);
  ushort* VTb = Kb + (4u << 20);
  ushort* ctx = VTb + (4u << 20);         // 4M elems; doubles as Xq scratch
  ushort* Xqb = ctx;
  ushort* Xkb = (ushort*)d_out;
  ushort* Xvb = (ushort*)d_out + (4u << 20);

  dim3 blk(256);

  CvtArgs ca;
  ca.src[0] = Wq;    ca.dst[0] = Wqb;
  ca.src[1] = Wk;    ca.dst[1] = Wkb;
  ca.src[2] = Wv;    ca.dst[2] = Wvb;
  ca.src[3] = Wo;    ca.dst[3] = Wob;
  ca.src[4] = query; ca.dst[4] = Xqb;
  ca.src[5] = key_;  ca.dst[5] = Xkb;
  ca.src[6] = value; ca.dst[6] = Xvb;
  cvt_all<<<8192, blk, 0, stream>>>(ca);

  QKVArgs a;
  a.A0 = Xqb;  a.A1 = Xkb;  a.A2 = Xvb;
  a.W0 = Wqb;  a.W1 = Wkb;  a.W2 = Wvb;
  a.b0 = bq;   a.b1 = bk;   a.b2 = bv;
  a.Qo = Qb;   a.Ko = Kb;   a.Vo = VTb;
  qkv_gemm<<<dim3(32, 8, 3), blk, 0, stream>>>(a);

  attn_fwd<<<dim3(16, 32), blk, 0, stream>>>(Qb, Kb, VTb, ctx);

  out_gemm<<<dim3(64, 8), blk, 0, stream>>>(ctx, Wob, bo, (float*)d_out);
}